// Round 9
// baseline (519.553 us; speedup 1.0000x reference)
//
#include <hip/hip_runtime.h>
#include <math.h>

// Problem constants
constexpr int cB = 2, cS = 4096, cHID = 1024, cNH = 16, cHD = 64, cNL = 128, cSEG = 32, cD = 1024, cBH = 32;
constexpr float cSCALE = 0.35355339059327373f;   // 1/sqrt(sqrt(64))

typedef _Float16 f16x8 __attribute__((ext_vector_type(8)));
typedef float f32x4 __attribute__((ext_vector_type(4)));

__device__ inline void gload_lds16(const void* g, void* l) {
    __builtin_amdgcn_global_load_lds(
        (const __attribute__((address_space(1))) void*)g,
        (__attribute__((address_space(3))) void*)l, 16, 0, 0);
}

// ---------------------------------------------------------------------------
// transpose+cast W (K x N fp32) -> WT (N x K fp16)
// ---------------------------------------------------------------------------
__global__ __launch_bounds__(256) void wcast_t(
    const float* __restrict__ Wq, const float* __restrict__ Wk,
    const float* __restrict__ Wv, const float* __restrict__ Wo,
    _Float16* __restrict__ WqT, _Float16* __restrict__ WkT,
    _Float16* __restrict__ WvT, _Float16* __restrict__ WoT)
{
    __shared__ float tile[32][33];
    const int wsel = blockIdx.z;
    const float* W = (wsel == 0) ? Wq : (wsel == 1 ? Wk : (wsel == 2 ? Wv : Wo));
    _Float16* WT   = (wsel == 0) ? WqT : (wsel == 1 ? WkT : (wsel == 2 ? WvT : WoT));
    const int n0 = blockIdx.x * 32, k0 = blockIdx.y * 32;
    const int t = threadIdx.x;
    const int r = t >> 3, c = (t & 7) * 4;
    float4 v = *reinterpret_cast<const float4*>(W + (size_t)(k0 + r) * cD + n0 + c);
    tile[r][c] = v.x; tile[r][c + 1] = v.y; tile[r][c + 2] = v.z; tile[r][c + 3] = v.w;
    __syncthreads();
    union { _Float16 h[4]; ushort4 u; } p;
    p.h[0] = (_Float16)tile[c + 0][r]; p.h[1] = (_Float16)tile[c + 1][r];
    p.h[2] = (_Float16)tile[c + 2][r]; p.h[3] = (_Float16)tile[c + 3][r];
    *reinterpret_cast<ushort4*>(WT + (size_t)(n0 + r) * cHID + k0 + c) = p.u;
}

// ---------------------------------------------------------------------------
// xm_kernel (+fused cast_x), 4x D-split: grid (256, 4) x 64 thr.
// Xm[b*128+l][:] = (1/32) sum_j mask*X ; mbar = mean mask ; Xh = (f16)X
// ---------------------------------------------------------------------------
__global__ __launch_bounds__(64) void xm_kernel(
    const float* __restrict__ X, const float* __restrict__ mask,
    float* __restrict__ Xm, float* __restrict__ mbar, _Float16* __restrict__ Xh)
{
    const int bl = blockIdx.x;          // b*128 + l
    const int q  = blockIdx.y;          // D quarter
    const int b = bl >> 7, l = bl & 127;
    const int c = q * 256 + threadIdx.x * 4;
    float4 a = {0.f, 0.f, 0.f, 0.f};
    float msum = 0.f;
    for (int j = 0; j < cSEG; ++j) {
        float m = mask[b * cS + l * cSEG + j];
        size_t roff = ((size_t)(b * cS + l * cSEG + j)) * cHID + c;
        float4 x = *reinterpret_cast<const float4*>(X + roff);
        union { _Float16 h[4]; ushort4 u; } p;
        p.h[0] = (_Float16)x.x; p.h[1] = (_Float16)x.y;
        p.h[2] = (_Float16)x.z; p.h[3] = (_Float16)x.w;
        *reinterpret_cast<ushort4*>(Xh + roff) = p.u;
        a.x += m * x.x; a.y += m * x.y; a.z += m * x.z; a.w += m * x.w;
        msum += m;
    }
    const float inv = 1.0f / cSEG;
    a.x *= inv; a.y *= inv; a.z *= inv; a.w *= inv;
    *reinterpret_cast<float4*>(Xm + (size_t)bl * cHID + c) = a;
    if (q == 0 && threadIdx.x == 0) mbar[bl] = msum * inv;
}

// ---------------------------------------------------------------------------
// f16 MFMA GEMM: QKV. BK=64, XOR-swizzled LDS, XCD-aware blocks.
// grid: dim3(512, 1, 3). bid&7 = XCD -> owns m-band [xcd*8, xcd*8+8) x all n.
// ---------------------------------------------------------------------------
__global__ __launch_bounds__(256) void qkv_gemm_f16(
    const _Float16* __restrict__ Xh, const float* __restrict__ mask,
    const _Float16* __restrict__ WqT, const _Float16* __restrict__ WkT, const _Float16* __restrict__ WvT,
    const float* __restrict__ bq, const float* __restrict__ bk, const float* __restrict__ bv,
    _Float16* __restrict__ Qh, _Float16* __restrict__ Kh, _Float16* __restrict__ Vh)
{
    __shared__ __align__(16) _Float16 As[128 * 64];
    __shared__ __align__(16) _Float16 Bs[128 * 64];
    const int wsel = blockIdx.z;
    const _Float16* WT = (wsel == 0) ? WqT : (wsel == 1 ? WkT : WvT);
    const float* bias  = (wsel == 0) ? bq  : (wsel == 1 ? bk  : bv);
    _Float16* Y        = (wsel == 0) ? Qh  : (wsel == 1 ? Kh  : Vh);
    const int orig = blockIdx.x;
    const int xcd = orig & 7, idx = orig >> 3;
    const int n0 = (idx & 7) * 128;
    const int m0 = (xcd * 8 + (idx >> 3)) * 128;
    const int t = threadIdx.x;
    const int wave = t >> 6, lane = t & 63;
    const int wm = (wave >> 1) * 64, wn = (wave & 1) * 64;
    const int quad = lane >> 4, l15 = lane & 15;
    const int srow = wave * 8 + (lane >> 3);              // staging row in 8-row chunk
    const int scol = ((lane & 7) ^ (lane >> 3)) * 8;      // pre-swizzled global granule

    f32x4 acc[4][4];
#pragma unroll
    for (int i = 0; i < 4; ++i)
#pragma unroll
        for (int j = 0; j < 4; ++j) acc[i][j] = (f32x4){0.f, 0.f, 0.f, 0.f};

    for (int k0 = 0; k0 < cHID; k0 += 64) {
        const _Float16* aSrc = Xh + (size_t)(m0 + srow) * cHID + k0 + scol;
        const _Float16* bSrc = WT + (size_t)(n0 + srow) * cHID + k0 + scol;
#pragma unroll
        for (int i = 0; i < 4; ++i) {
            gload_lds16(aSrc + (size_t)(i * 32) * cHID, &As[(wave * 8 + i * 32) * 64]);
            gload_lds16(bSrc + (size_t)(i * 32) * cHID, &Bs[(wave * 8 + i * 32) * 64]);
        }
        __syncthreads();
        f16x8 af[2][4], bf[2][4];
#pragma unroll
        for (int kh = 0; kh < 2; ++kh) {
            const int cg = ((kh * 4 + quad) ^ (l15 & 7)) * 8;   // swizzled read granule
#pragma unroll
            for (int mt = 0; mt < 4; ++mt)
                af[kh][mt] = *reinterpret_cast<const f16x8*>(&As[(wm + mt * 16 + l15) * 64 + cg]);
#pragma unroll
            for (int nt = 0; nt < 4; ++nt)
                bf[kh][nt] = *reinterpret_cast<const f16x8*>(&Bs[(wn + nt * 16 + l15) * 64 + cg]);
        }
#pragma unroll
        for (int kh = 0; kh < 2; ++kh)
#pragma unroll
            for (int mt = 0; mt < 4; ++mt)
#pragma unroll
                for (int nt = 0; nt < 4; ++nt)
                    acc[mt][nt] = __builtin_amdgcn_mfma_f32_16x16x32_f16(af[kh][mt], bf[kh][nt], acc[mt][nt], 0, 0, 0);
        __syncthreads();
    }
#pragma unroll
    for (int mt = 0; mt < 4; ++mt) {
#pragma unroll
        for (int r = 0; r < 4; ++r) {
            int R = m0 + wm + mt * 16 + quad * 4 + r;
            int b = R >> 12, s = R & (cS - 1);
            float msc = (wsel < 2) ? mask[b * cS + s] * cSCALE : 1.0f;
#pragma unroll
            for (int nt = 0; nt < 4; ++nt) {
                int Cc = n0 + wn + nt * 16 + l15;
                int h = Cc >> 6, d = Cc & 63;
                float val = (acc[mt][nt][r] + bias[Cc]) * msc;
                Y[((size_t)(b * cNH + h) * cS + s) * cHD + d] = (_Float16)val;
            }
        }
    }
}

// ---------------------------------------------------------------------------
// f16 MFMA GEMM: out = ctxh @ Wo + bo  (BK=64, swizzled, XCD-aware)
// grid: dim3(512)
// ---------------------------------------------------------------------------
__global__ __launch_bounds__(256) void out_gemm_f16(
    const _Float16* __restrict__ Ah, const _Float16* __restrict__ WT,
    const float* __restrict__ bias, float* __restrict__ Y)
{
    __shared__ __align__(16) _Float16 As[128 * 64];
    __shared__ __align__(16) _Float16 Bs[128 * 64];
    const int orig = blockIdx.x;
    const int xcd = orig & 7, idx = orig >> 3;
    const int n0 = (idx & 7) * 128;
    const int m0 = (xcd * 8 + (idx >> 3)) * 128;
    const int t = threadIdx.x;
    const int wave = t >> 6, lane = t & 63;
    const int wm = (wave >> 1) * 64, wn = (wave & 1) * 64;
    const int quad = lane >> 4, l15 = lane & 15;
    const int srow = wave * 8 + (lane >> 3);
    const int scol = ((lane & 7) ^ (lane >> 3)) * 8;

    f32x4 acc[4][4];
#pragma unroll
    for (int i = 0; i < 4; ++i)
#pragma unroll
        for (int j = 0; j < 4; ++j) acc[i][j] = (f32x4){0.f, 0.f, 0.f, 0.f};

    for (int k0 = 0; k0 < cD; k0 += 64) {
        const _Float16* aSrc = Ah + (size_t)(m0 + srow) * cD + k0 + scol;
        const _Float16* bSrc = WT + (size_t)(n0 + srow) * cD + k0 + scol;
#pragma unroll
        for (int i = 0; i < 4; ++i) {
            gload_lds16(aSrc + (size_t)(i * 32) * cD, &As[(wave * 8 + i * 32) * 64]);
            gload_lds16(bSrc + (size_t)(i * 32) * cD, &Bs[(wave * 8 + i * 32) * 64]);
        }
        __syncthreads();
        f16x8 af[2][4], bf[2][4];
#pragma unroll
        for (int kh = 0; kh < 2; ++kh) {
            const int cg = ((kh * 4 + quad) ^ (l15 & 7)) * 8;
#pragma unroll
            for (int mt = 0; mt < 4; ++mt)
                af[kh][mt] = *reinterpret_cast<const f16x8*>(&As[(wm + mt * 16 + l15) * 64 + cg]);
#pragma unroll
            for (int nt = 0; nt < 4; ++nt)
                bf[kh][nt] = *reinterpret_cast<const f16x8*>(&Bs[(wn + nt * 16 + l15) * 64 + cg]);
        }
#pragma unroll
        for (int kh = 0; kh < 2; ++kh)
#pragma unroll
            for (int mt = 0; mt < 4; ++mt)
#pragma unroll
                for (int nt = 0; nt < 4; ++nt)
                    acc[mt][nt] = __builtin_amdgcn_mfma_f32_16x16x32_f16(af[kh][mt], bf[kh][nt], acc[mt][nt], 0, 0, 0);
        __syncthreads();
    }
#pragma unroll
    for (int mt = 0; mt < 4; ++mt) {
#pragma unroll
        for (int r = 0; r < 4; ++r) {
            int R = m0 + wm + mt * 16 + quad * 4 + r;
#pragma unroll
            for (int nt = 0; nt < 4; ++nt) {
                int Cc = n0 + wn + nt * 16 + l15;
                Y[(size_t)R * cHID + Cc] = acc[mt][nt][r] + bias[Cc];
            }
        }
    }
}

// ---------------------------------------------------------------------------
// Landmark GEMM (fp32, exact path). Emits f16 Qlh/Klh for MFMA consumers.
// ---------------------------------------------------------------------------
__global__ __launch_bounds__(256) void lgemm(
    const float* __restrict__ Xm, const float* __restrict__ mbar,
    const float* __restrict__ Wq, const float* __restrict__ bq,
    const float* __restrict__ Wk, const float* __restrict__ bk,
    float* __restrict__ Ql, float* __restrict__ Kl,
    _Float16* __restrict__ Qlh, _Float16* __restrict__ Klh)
{
    __shared__ __align__(16) float As[16][68];
    __shared__ __align__(16) float Bs[16][68];
    const int tid = threadIdx.x;
    const int wsel = blockIdx.z;
    const float* W    = wsel ? Wk : Wq;
    const float* bias = wsel ? bk : bq;
    float* Yl         = wsel ? Kl : Ql;
    _Float16* Ylh     = wsel ? Klh : Qlh;
    const int c0 = blockIdx.x * 64, r0 = blockIdx.y * 64;
    const int tx = tid & 15, ty = tid >> 4;
    const int am = tid >> 2, ak = (tid & 3) * 4;
    const int bkk = tid >> 4, bn = (tid & 15) * 4;

    float acc[4][4] = {};
    for (int k0 = 0; k0 < cHID; k0 += 16) {
        float4 a4 = *reinterpret_cast<const float4*>(Xm + (size_t)(r0 + am) * cHID + k0 + ak);
        As[ak + 0][am] = a4.x; As[ak + 1][am] = a4.y; As[ak + 2][am] = a4.z; As[ak + 3][am] = a4.w;
        float4 b4 = *reinterpret_cast<const float4*>(W + (size_t)(k0 + bkk) * cD + c0 + bn);
        *reinterpret_cast<float4*>(&Bs[bkk][bn]) = b4;
        __syncthreads();
#pragma unroll
        for (int kk = 0; kk < 16; ++kk) {
            float4 av  = *reinterpret_cast<const float4*>(&As[kk][ty * 4]);
            float4 bv4 = *reinterpret_cast<const float4*>(&Bs[kk][tx * 4]);
            float a_[4] = {av.x, av.y, av.z, av.w};
            float b_[4] = {bv4.x, bv4.y, bv4.z, bv4.w};
#pragma unroll
            for (int i = 0; i < 4; ++i)
#pragma unroll
                for (int j = 0; j < 4; ++j) acc[i][j] += a_[i] * b_[j];
        }
        __syncthreads();
    }
#pragma unroll
    for (int i = 0; i < 4; ++i) {
        int r = r0 + ty * 4 + i;          // b*128 + l
        int b = r >> 7, l = r & 127;
        float mb = mbar[r];
#pragma unroll
        for (int j = 0; j < 4; ++j) {
            int c = c0 + tx * 4 + j;
            int h = c >> 6, d = c & 63;
            float val = (acc[i][j] + mb * bias[c]) * cSCALE;
            size_t idx = ((size_t)(b * cNH + h) * cNL + l) * cHD + d;
            Yl[idx] = val;
            Ylh[idx] = (_Float16)val;
        }
    }
}

// ---------------------------------------------------------------------------
// k2 softmax chain (fp32-clean path)
// ---------------------------------------------------------------------------
__global__ __launch_bounds__(128) void k2_softmax(
    const float* __restrict__ Ql, const float* __restrict__ Kl, float* __restrict__ k2)
{
    __shared__ __align__(16) float qrow[64];
    __shared__ float red[128];
    int bh = blockIdx.x >> 7, i = blockIdx.x & 127;
    int j = threadIdx.x;
    if (j < 64) qrow[j] = Ql[(bh * cNL + i) * cHD + j];
    __syncthreads();
    const float4* q4  = reinterpret_cast<const float4*>(qrow);
    const float4* kl4 = reinterpret_cast<const float4*>(Kl + (bh * cNL + j) * cHD);
    float dot = 0.f;
#pragma unroll
    for (int u = 0; u < 16; ++u) {
        float4 a = q4[u], b = kl4[u];
        dot += a.x * b.x + a.y * b.y + a.z * b.z + a.w * b.w;
    }
    red[j] = dot; __syncthreads();
    for (int off = 64; off > 0; off >>= 1) { if (j < off) red[j] = fmaxf(red[j], red[j + off]); __syncthreads(); }
    float m = red[0]; __syncthreads();
    float e = expf(dot - m);
    red[j] = e; __syncthreads();
    for (int off = 64; off > 0; off >>= 1) { if (j < off) red[j] += red[j + off]; __syncthreads(); }
    k2[(bh * cNL + i) * cNL + j] = e / red[0];
}

__global__ __launch_bounds__(128) void colsum_max(const float* __restrict__ k2, int* __restrict__ cmax)
{
    __shared__ float red[128];
    int bh = blockIdx.x, j = threadIdx.x;
    float s = 0.f;
    for (int i = 0; i < cNL; ++i) s += k2[(bh * cNL + i) * cNL + j];
    red[j] = s; __syncthreads();
    for (int off = 64; off > 0; off >>= 1) { if (j < off) red[j] = fmaxf(red[j], red[j + off]); __syncthreads(); }
    if (j == 0) atomicMax(cmax, __float_as_int(red[0]));
}

// ---------------------------------------------------------------------------
// Helpers for fused nys+k3v
// ---------------------------------------------------------------------------
__device__ inline void split2(float v, _Float16& h, _Float16& l) {
    h = (_Float16)v;
    l = (_Float16)(v - (float)h);
}
__device__ inline unsigned short f16bits(_Float16 h) { return __builtin_bit_cast(unsigned short, h); }

#define NYS_MFMA(a, b, c) __builtin_amdgcn_mfma_f32_16x16x32_f16((a), (b), (c), 0, 0, 0)

// preload left frags from LDS plane rows (contiguous b128)
#define NYS_PRELOAD_LDS(PH, PL, LH, LL)                                                 \
    {                                                                                   \
        _Pragma("unroll")                                                               \
        for (int mt_ = 0; mt_ < 4; ++mt_) {                                             \
            const int rowL_ = wr * 64 + mt_ * 16 + l15;                                 \
            _Pragma("unroll")                                                           \
            for (int k0_ = 0; k0_ < 4; ++k0_) {                                         \
                LH[mt_][k0_] = *reinterpret_cast<const f16x8*>(&PH[rowL_ * 136 + k0_ * 32 + quad * 8]); \
                LL[mt_][k0_] = *reinterpret_cast<const f16x8*>(&PL[rowL_ * 136 + k0_ * 32 + quad * 8]); \
            }                                                                           \
        }                                                                               \
    }

// preload left frags from global fp32 rows (split at load)
#define NYS_PRELOAD_G(GP, LH, LL)                                                       \
    {                                                                                   \
        _Pragma("unroll")                                                               \
        for (int mt_ = 0; mt_ < 4; ++mt_) {                                             \
            const int rowL_ = wr * 64 + mt_ * 16 + l15;                                 \
            _Pragma("unroll")                                                           \
            for (int k0_ = 0; k0_ < 4; ++k0_) {                                         \
                const float* s_ = GP + rowL_ * 128 + k0_ * 32 + quad * 8;               \
                float4 v0_ = *reinterpret_cast<const float4*>(s_);                      \
                float4 v1_ = *reinterpret_cast<const float4*>(s_ + 4);                  \
                union { f16x8 v; _Float16 e[8]; } hh_, ll_;                             \
                split2(v0_.x, hh_.e[0], ll_.e[0]); split2(v0_.y, hh_.e[1], ll_.e[1]);   \
                split2(v0_.z, hh_.e[2], ll_.e[2]); split2(v0_.w, hh_.e[3], ll_.e[3]);   \
                split2(v1_.x, hh_.e[4], ll_.e[4]); split2(v1_.y, hh_.e[5], ll_.e[5]);   \
                split2(v1_.z, hh_.e[6], ll_.e[6]); split2(v1_.w, hh_.e[7], ll_.e[7]);   \
                LH[mt_][k0_] = hh_.v; LL[mt_][k0_] = ll_.v;                             \
            }                                                                           \
        }                                                                               \
    }

// product over wave's 64x32 region; right-operand from LDS planes
#define NYS_PRODUCT_LDS(PH, PL, LH, LL)                                                 \
    {                                                                                   \
        _Pragma("unroll")                                                               \
        for (int mt_ = 0; mt_ < 4; ++mt_)                                               \
            _Pragma("unroll")                                                           \
            for (int nt_ = 0; nt_ < 2; ++nt_) acc[mt_][nt_] = (f32x4){0.f, 0.f, 0.f, 0.f}; \
        _Pragma("unroll")                                                               \
        for (int nt_ = 0; nt_ < 2; ++nt_) {                                             \
            _Pragma("unroll")                                                           \
            for (int k0_ = 0; k0_ < 4; ++k0_) {                                         \
                const int boff_ = (wcb + nt_ * 16) * 136 + k0_ * 32 + quad * 8;         \
                f16x8 bh_ = *reinterpret_cast<const f16x8*>(&PH[boff_]);                \
                f16x8 bl_ = *reinterpret_cast<const f16x8*>(&PL[boff_]);                \
                _Pragma("unroll")                                                       \
                for (int mt_ = 0; mt_ < 4; ++mt_) {                                     \
                    acc[mt_][nt_] = NYS_MFMA(LH[mt_][k0_], bh_, acc[mt_][nt_]);         \
                    acc[mt_][nt_] = NYS_MFMA(LL[mt_][k0_], bh_, acc[mt_][nt_]);         \
                    acc[mt_][nt_] = NYS_MFMA(LH[mt_][k0_], bl_, acc[mt_][nt_]);         \
                }                                                                       \
            }                                                                           \
        }                                                                               \
    }

// product over wave's 64x32 region; right-operand from global fp32 (cols via symmetry)
#define NYS_PRODUCT_G(GP, LH, LL)                                                       \
    {                                                                                   \
        _Pragma("unroll")                                                               \
        for (int mt_ = 0; mt_ < 4; ++mt_)                                               \
            _Pragma("unroll")                                                           \
            for (int nt_ = 0; nt_ < 2; ++nt_) acc[mt_][nt_] = (f32x4){0.f, 0.f, 0.f, 0.f}; \
        _Pragma("unroll")                                                               \
        for (int nt_ = 0; nt_ < 2; ++nt_) {                                             \
            _Pragma("unroll")                                                           \
            for (int k0_ = 0; k0_ < 4; ++k0_) {                                         \
                const float* s_ = GP + (wcb + nt_ * 16) * 128 + k0_ * 32 + quad * 8;    \
                float4 v0_ = *reinterpret_cast<const float4*>(s_);                      \
                float4 v1_ = *reinterpret_cast<const float4*>(s_ + 4);                  \
                union { f16x8 v; _Float16 e[8]; } bh_, bl_;                             \
                split2(v0_.x, bh_.e[0], bl_.e[0]); split2(v0_.y, bh_.e[1], bl_.e[1]);   \
                split2(v0_.z, bh_.e[2], bl_.e[2]); split2(v0_.w, bh_.e[3], bl_.e[3]);   \
                split2(v1_.x, bh_.e[4], bl_.e[4]); split2(v1_.y, bh_.e[5], bl_.e[5]);   \
                split2(v1_.z, bh_.e[6], bl_.e[6]); split2(v1_.w, bh_.e[7], bl_.e[7]);   \
                _Pragma("unroll")                                                       \
                for (int mt_ = 0; mt_ < 4; ++mt_) {                                     \
                    acc[mt_][nt_] = NYS_MFMA(LH[mt_][k0_], bh_.v, acc[mt_][nt_]);       \
                    acc[mt_][nt_] = NYS_MFMA(LL[mt_][k0_], bh_.v, acc[mt_][nt_]);       \
                    acc[mt_][nt_] = NYS_MFMA(LH[mt_][k0_], bl_.v, acc[mt_][nt_]);       \
                }                                                                       \
            }                                                                           \
        }                                                                               \
    }

// ---------------------------------------------------------------------------
// nys_k3v fused: blocks [0,32) run symmetric Newton-Schulz (one per bh, 8
// waves, A-matrix in global fp32, W planes in 68KB LDS); blocks [32,544) run
// the barrier-free k3v flash-prefill (4 waves; threads >=256 exit).
// Independent roles -> true overlap: nys occupies 32 CUs, k3v fills the rest.
// ---------------------------------------------------------------------------
__global__ __launch_bounds__(512, 2) void nys_k3v(
    const float* __restrict__ k2, const int* __restrict__ cmax,
    float* __restrict__ Ag_all, float* __restrict__ Mg0, float* __restrict__ Mg1,
    const _Float16* __restrict__ Qlh, const _Float16* __restrict__ Kh,
    const _Float16* __restrict__ VTh, const float* __restrict__ mask,
    float* __restrict__ Opart, float* __restrict__ mpart, float* __restrict__ spart)
{
    __shared__ __align__(16) _Float16 SMEM[2 * 128 * 136];   // 68 KB

    if (blockIdx.x < 32) {
        // ================= NYS role =================
        _Float16* Wh = SMEM;
        _Float16* Wl = SMEM + 128 * 136;
        const int bh = blockIdx.x;
        const int t = threadIdx.x;
        const int wave = t >> 6, lane = t & 63;
        const int wr = wave >> 2, wc = wave & 3;          // 2 row-groups x 4 col-groups
        const int quad = lane >> 4, l15 = lane & 15;
        const int wcb = wc * 32 + l15;
        const float* Kg = k2 + (size_t)bh * 16384;
        float* Ag   = Ag_all + (size_t)bh * 16384;
        float* Mg0b = Mg0 + (size_t)bh * 16384;
        float* Mg1b = Mg1 + (size_t)bh * 16384;
        const float sc = sqrtf(1.0f / __int_as_float(*cmax));

        // stage Kp = K*sqrt(1/c) into W planes
        {
            const int row = t >> 2, c0 = (t & 3) * 32;
            const float* src = Kg + row * 128 + c0;
            _Float16* dh = &Wh[row * 136 + c0];
            _Float16* dl = &Wl[row * 136 + c0];
#pragma unroll
            for (int u = 0; u < 32; u += 4) {
                float4 v = *reinterpret_cast<const float4*>(src + u);
                ushort4 ph, pl; _Float16 h, l;
                split2(v.x * sc, h, l); ph.x = f16bits(h); pl.x = f16bits(l);
                split2(v.y * sc, h, l); ph.y = f16bits(h); pl.y = f16bits(l);
                split2(v.z * sc, h, l); ph.z = f16bits(h); pl.z = f16bits(l);
                split2(v.w * sc, h, l); ph.w = f16bits(h); pl.w = f16bits(l);
                *reinterpret_cast<ushort4*>(dh + u) = ph;
                *reinterpret_cast<ushort4*>(dl + u) = pl;
            }
        }
        __syncthreads();

        f32x4 acc[4][2];
        f16x8 Fh[4][4], Fl[4][4];

        // A1 = Kp @ Kp^T -> Ag (fp32 exact)
        NYS_PRELOAD_LDS(Wh, Wl, Fh, Fl);
        NYS_PRODUCT_LDS(Wh, Wl, Fh, Fl);
#pragma unroll
        for (int mt = 0; mt < 4; ++mt)
#pragma unroll
            for (int nt = 0; nt < 2; ++nt) {
                const int col = wcb + nt * 16;
                const int rb  = wr * 64 + mt * 16 + quad * 4;
                float4 mv;
#pragma unroll
                for (int r = 0; r < 4; ++r) ((float*)&mv)[r] = acc[mt][nt][r];
                *reinterpret_cast<float4*>(&Ag[col * 128 + rb]) = mv;   // symmetric: col-major == row-major
            }
        __syncthreads();

        for (int it = 0; it < 6; ++it) {
            // a: preload A-left frags from global rows (reused 3x)
            NYS_PRELOAD_G(Ag, Fh, Fl);
            // b: Z = A @ A (right from global via symmetry)
            NYS_PRODUCT_G(Ag, Fh, Fl);
            // c: B2 = 15I - 7A + Z -> W planes (A C-layout from global)
#pragma unroll
            for (int mt = 0; mt < 4; ++mt)
#pragma unroll
                for (int nt = 0; nt < 2; ++nt) {
                    const int col = wcb + nt * 16;
                    const int rb  = wr * 64 + mt * 16 + quad * 4;
                    float4 av = *reinterpret_cast<const float4*>(&Ag[col * 128 + rb]);
                    ushort4 ph, pl;
#pragma unroll
                    for (int r = 0; r < 4; ++r) {
                        float v = ((rb + r) == col ? 15.0f : 0.0f) - 7.0f * ((float*)&av)[r] + acc[mt][nt][r];
                        _Float16 h, l; split2(v, h, l);
                        ((unsigned short*)&ph)[r] = f16bits(h);
                        ((unsigned short*)&pl)[r] = f16bits(l);
                    }
                    *reinterpret_cast<ushort4*>(&Wh[col * 136 + rb]) = ph;
                    *reinterpret_cast<ushort4*>(&Wl[col * 136 + rb]) = pl;
                }
            __syncthreads();                       // #1: B2 visible
            // d: P3 = A @ B2
            NYS_PRODUCT_LDS(Wh, Wl, Fh, Fl);
            __syncthreads();                       // #2: B2 reads done
            // e: B3 = 13I - P3 -> W planes; it0: M1 = 0.25*B3 -> Mg0
#pragma unroll
            for (int mt = 0; mt < 4; ++mt)
#pragma unroll
                for (int nt = 0; nt < 2; ++nt) {
                    const int col = wcb + nt * 16;
                    const int rb  = wr * 64 + mt * 16 + quad * 4;
                    ushort4 ph, pl; float4 mv;
#pragma unroll
                    for (int r = 0; r < 4; ++r) {
                        float v = ((rb + r) == col ? 13.0f : 0.0f) - acc[mt][nt][r];
                        _Float16 h, l; split2(v, h, l);
                        ((unsigned short*)&ph)[r] = f16bits(h);
                        ((unsigned short*)&pl)[r] = f16bits(l);
                        ((float*)&mv)[r] = 0.25f * v;
                    }
                    *reinterpret_cast<ushort4*>(&Wh[col * 136 + rb]) = ph;
                    *reinterpret_cast<ushort4*>(&Wl[col * 136 + rb]) = pl;
                    if (it == 0)
                        *reinterpret_cast<float4*>(&Mg0b[col * 128 + rb]) = mv;
                }
            __syncthreads();                       // #3: B3 visible
            // f: A4 = A @ B3
            NYS_PRODUCT_LDS(Wh, Wl, Fh, Fl);
            // g: A' = 0.25*A4 -> Ag (fp32; all A readers passed barrier #1)
#pragma unroll
            for (int mt = 0; mt < 4; ++mt)
#pragma unroll
                for (int nt = 0; nt < 2; ++nt) {
                    const int col = wcb + nt * 16;
                    const int rb  = wr * 64 + mt * 16 + quad * 4;
                    float4 mv;
#pragma unroll
                    for (int r = 0; r < 4; ++r) ((float*)&mv)[r] = 0.25f * acc[mt][nt][r];
                    *reinterpret_cast<float4*>(&Ag[col * 128 + rb]) = mv;
                }
            // M' = 0.25 * M @ B3 (global fp32 double-buffer; k0-sliced frags)
            if (it >= 1) {
                const float* Mr = (it & 1) ? Mg0b : Mg1b;
                float*       Mw = (it & 1) ? Mg1b : Mg0b;
#pragma unroll
                for (int mt = 0; mt < 4; ++mt)
#pragma unroll
                    for (int nt = 0; nt < 2; ++nt) acc[mt][nt] = (f32x4){0.f, 0.f, 0.f, 0.f};
#pragma unroll
                for (int k0 = 0; k0 < 4; ++k0) {
                    f16x8 Mh[4], Ml[4];
#pragma unroll
                    for (int mt = 0; mt < 4; ++mt) {
                        const int rowL = wr * 64 + mt * 16 + l15;
                        const float* src = Mr + rowL * 128 + k0 * 32 + quad * 8;
                        float4 v0 = *reinterpret_cast<const float4*>(src);
                        float4 v1 = *reinterpret_cast<const float4*>(src + 4);
                        union { f16x8 v; _Float16 e[8]; } hh, ll;
                        split2(v0.x, hh.e[0], ll.e[0]); split2(v0.y, hh.e[1], ll.e[1]);
                        split2(v0.z, hh.e[2], ll.e[2]); split2(v0.w, hh.e[3], ll.e[3]);
                        split2(v1.x, hh.e[4], ll.e[4]); split2(v1.y, hh.e[5], ll.e[5]);
                        split2(v1.z, hh.e[6], ll.e[6]); split2(v1.w, hh.e[7], ll.e[7]);
                        Mh[mt] = hh.v; Ml[mt] = ll.v;
                    }
#pragma unroll
                    for (int nt = 0; nt < 2; ++nt) {
                        const int boff = (wcb + nt * 16) * 136 + k0 * 32 + quad * 8;
                        f16x8 bh_ = *reinterpret_cast<const f16x8*>(&Wh[boff]);
                        f16x8 bl_ = *reinterpret_cast<const f16x8*>(&Wl[boff]);
#pragma unroll
                        for (int mt = 0; mt < 4; ++mt) {
                            acc[mt][nt] = NYS_MFMA(Mh[mt], bh_, acc[mt][nt]);
                            acc[mt][nt] = NYS_MFMA(Ml[mt], bh_, acc[mt][nt]);
                            acc[mt][nt] = NYS_MFMA(Mh[mt], bl_, acc[mt][nt]);
                        }
                    }
                }
#pragma unroll
                for (int mt = 0; mt < 4; ++mt)
#pragma unroll
                    for (int nt = 0; nt < 2; ++nt) {
                        const int col = wcb + nt * 16;
                        const int rb  = wr * 64 + mt * 16 + quad * 4;
                        float4 mv;
#pragma unroll
                        for (int r = 0; r < 4; ++r) ((float*)&mv)[r] = 0.25f * acc[mt][nt][r];
                        *reinterpret_cast<float4*>(&Mw[col * 128 + rb]) = mv;
                    }
            }
            __syncthreads();                       // #4: A'/M' visible; W free
        }
        // M6 ends in Mg1 (it5 writes Mg1).
    } else {
        // ================= K3V role (barrier-free, 4 waves) =================
        if (threadIdx.x >= 256) return;
        _Float16* Ps = SMEM;                       // wave-private row bands [128*72]
        const int id = blockIdx.x - 32;
        const int z = id & 15, bh = id >> 4;
        const int b = bh >> 4;
        const int sbase = z * 256;
        const int t = threadIdx.x;
        const int wave = t >> 6, lane = t & 63;
        const int quad = lane >> 4, l15 = lane & 15;

        f16x8 aq[2][2];
        const _Float16* qlg = Qlh + (size_t)bh * cNL * cHD;
#pragma unroll
        for (int mt = 0; mt < 2; ++mt)
#pragma unroll
            for (int k0 = 0; k0 < 2; ++k0)
                aq[mt][k0] = *reinterpret_cast<const f16x8*>(
                    qlg + (size_t)(wave * 32 + mt * 16 + l15) * cHD + k0 * 32 + quad * 8);

        float mrun[2][4], srun[2][4];
        f32x4 accO[2][4];
#pragma unroll
        for (int mt = 0; mt < 2; ++mt)
#pragma unroll
            for (int r = 0; r < 4; ++r) { mrun[mt][r] = -1e30f; srun[mt][r] = 0.f; }
#pragma unroll
        for (int mt = 0; mt < 2; ++mt)
#pragma unroll
            for (int dt = 0; dt < 4; ++dt) accO[mt][dt] = (f32x4){0.f, 0.f, 0.f, 0.f};

        const _Float16* kg = Kh + (size_t)bh * cS * cHD;
        const _Float16* vg = VTh + (size_t)bh * cHD * cS;

        for (int step = 0; step < 4; ++step) {
            const int st = sbase + step * 64;
            f32x4 accS[2][4];
#pragma unroll
            for (int mt = 0; mt < 2; ++mt)
#pragma unroll
                for (int nt = 0; nt < 4; ++nt) accS[mt][nt] = (f32x4){0.f, 0.f, 0.f, 0.f};
#pragma unroll
            for (int k0 = 0; k0 < 2; ++k0)
#pragma unroll
                for (int nt = 0; nt < 4; ++nt) {
                    f16x8 bk = *reinterpret_cast<const f16x8*>(
                        kg + (size_t)(st + nt * 16 + l15) * cHD + k0 * 32 + quad * 8);
#pragma unroll
                    for (int mt = 0; mt < 2; ++mt)
                        accS[mt][nt] = __builtin_amdgcn_mfma_f32_16x16x32_f16(aq[mt][k0], bk, accS[mt][nt], 0, 0, 0);
                }
#pragma unroll
            for (int nt = 0; nt < 4; ++nt) {
                float pen = 1e9f * (1.0f - mask[b * cS + st + nt * 16 + l15]);
#pragma unroll
                for (int mt = 0; mt < 2; ++mt)
#pragma unroll
                    for (int r = 0; r < 4; ++r) accS[mt][nt][r] -= pen;
            }
#pragma unroll
            for (int mt = 0; mt < 2; ++mt) {
#pragma unroll
                for (int r = 0; r < 4; ++r) {
                    float tmax = fmaxf(fmaxf(accS[mt][0][r], accS[mt][1][r]),
                                       fmaxf(accS[mt][2][r], accS[mt][3][r]));
#pragma unroll
                    for (int w = 1; w < 16; w <<= 1) tmax = fmaxf(tmax, __shfl_xor(tmax, w, 16));
                    float mnew = fmaxf(mrun[mt][r], tmax);
                    float alpha = __expf(mrun[mt][r] - mnew);
                    float ts = 0.f;
#pragma unroll
                    for (int nt = 0; nt < 4; ++nt) {
                        float e = __expf(accS[mt][nt][r] - mnew);
                        accS[mt][nt][r] = e; ts += e;
                    }
#pragma unroll
                    for (int w = 1; w < 16; w <<= 1) ts += __shfl_xor(ts, w, 16);
                    srun[mt][r] = srun[mt][r] * alpha + ts;
                    mrun[mt][r] = mnew;
#pragma unroll
                    for (int dt = 0; dt < 4; ++dt) accO[mt][dt][r] *= alpha;
                }
            }
#pragma unroll
            for (int mt = 0; mt < 2; ++mt)
#pragma unroll
                for (int nt = 0; nt < 4; ++nt)
#pragma unroll
                    for (int r = 0; r < 4; ++r)
                        Ps[(wave * 32 + mt * 16 + quad * 4 + r) * 72 + nt * 16 + l15] =
                            (_Float16)accS[mt][nt][r];
#pragma unroll
            for (int k0 = 0; k0 < 2; ++k0) {
                f16x8 ap[2];
#pragma unroll
                for (int mt = 0; mt < 2; ++mt)
                    ap[mt] = *reinterpret_cast<const f16x8*>(
                        &Ps[(wave * 32 + mt * 16 + l15) * 72 + k0 * 32 + quad * 8]);
#pragma unroll
                for (int dt = 0; dt < 4; ++dt) {
                    f16x8 bv = *reinterpret_cast<const f16x8*>(
                        vg + (size_t)(dt * 16 + l15) * cS + st + k0 * 32 + quad * 8);
#pragma unroll
                    for (int mt = 0; mt < 2; ++mt)
                        accO[mt][dt] = __builtin_amdgcn_mfma_f32_16x16x32_f16(ap[mt], bv, accO[mt][dt], 0, 0, 0);
                }
            }
        }
        const int rowbase = bh * cNL + wave * 32;
#pragma unroll
        for (int mt = 0; mt < 2; ++mt)
#pragma unroll
            for (int dt = 0; dt < 4; ++dt)
#pragma unroll
                for (int r = 0; r < 4; ++r)
                    Opart[(size_t)(z * 4096 + rowbase + mt * 16 + quad * 4 + r) * cHD + dt * 16 + l15] =
                        accO[mt][dt][r];
        if (l15 == 0) {
#pragma unroll
            for (int mt = 0; mt < 2; ++mt)
#pragma unroll
                for (int r = 0; r < 4; ++r) {
                    int prow = z * 4096 + rowbase + mt * 16 + quad * 4 + r;
                    mpart[prow] = mrun[mt][r];
                    spart[prow] = srun[mt][r];
                }
        }
    }
}

// ---------------------------------------------------------------------------
// vtrans: Vh[bh][s][d] f16 -> VTh[bh][d][s] f16 (64x64 LDS tiles)
// ---------------------------------------------------------------------------
__global__ __launch_bounds__(256) void vtrans(const _Float16* __restrict__ Vh, _Float16* __restrict__ VTh)
{
    __shared__ ushort T[64][72];
    const int s0 = blockIdx.x * 64, bh = blockIdx.y;
    const int t = threadIdx.x;
    const _Float16* vb = Vh + ((size_t)bh * cS + s0) * cHD;
#pragma unroll
    for (int i = 0; i < 2; ++i) {
        int idx = t + i * 256;
        int row = idx >> 3, c8 = idx & 7;
        f16x8 v = *reinterpret_cast<const f16x8*>(vb + (size_t)row * cHD + c8 * 8);
#pragma unroll
        for (int j = 0; j < 8; ++j) T[row][c8 * 8 + j] = ((ushort*)&v)[j];
    }
    __syncthreads();
    _Float16* vt = VTh + (size_t)bh * cHD * cS;
#pragma unroll
    for (int i = 0; i < 2; ++i) {
        int idx = t + i * 256;
        int d = idx >> 3, s8 = idx & 7;
        f16x8 o;
#pragma unroll
        for (int j = 0; j < 8; ++j) ((ushort*)&o)[j] = T[s8 * 8 + j][d];
        *reinterpret_cast<f16x8*>(vt + (size_t)d * cS + s0 + s8 * 8) = o;
    }
}

// ---------------------------------------------------------------------------
// combine 16 chunk-partials
// ---------------------------------------------------------------------------
__global__ __launch_bounds__(256) void k3v_reduce(
    const float* __restrict__ Opart, const float* __restrict__ mpart,
    const float* __restrict__ spart, float* __restrict__ CV)
{
    const int t = threadIdx.x;
    const int row = blockIdx.x * 4 + (t >> 6);
    const int d = t & 63;
    float mstar = -1e30f;
#pragma unroll
    for (int z = 0; z < 16; ++z) mstar = fmaxf(mstar, mpart[z * 4096 + row]);
    float ssum = 0.f, acc = 0.f;
#pragma unroll
    for (int z = 0; z < 16; ++z) {
        float w = __expf(mpart[z * 4096 + row] - mstar);
        ssum += w * spart[z * 4096 + row];
        acc  += w * Opart[(size_t)(z * 4096 + row) * cHD + d];
    }
    CV[(size_t)row * cHD + d] = acc / ssum;
}

// ---------------------------------------------------------------------------
// w2_matmul: W2 = V6 @ CV with V6 = (K^T/c) @ M6 applied lazily:
//   U = M6 @ CV ; W2T[d][l] = (1/c) * sum_j k2[j][l] * U[j][d]
// ---------------------------------------------------------------------------
__global__ __launch_bounds__(256) void w2_matmul(
    const float* __restrict__ k2, const float* __restrict__ M6,
    const int* __restrict__ cmax, const float* __restrict__ CV,
    _Float16* __restrict__ W2T)
{
    __shared__ __align__(16) float CVs[128][68];
    __shared__ __align__(16) float Us[128][68];
    const int bh = blockIdx.x, t = threadIdx.x;
    const float invc = 1.0f / __int_as_float(*cmax);
    for (int k = 0; k < 32; ++k) { int idx = t + k * 256; CVs[idx >> 6][idx & 63] = CV[(size_t)bh * 8192 + idx]; }
    __syncthreads();
    const float* Mg = M6 + (size_t)bh * 16384;
    {
        const int tx = t & 15, ty = t >> 4;
        float acc[8][4] = {};
        for (int k = 0; k < 128; ++k) {
            float4 b4 = *reinterpret_cast<const float4*>(&CVs[k][tx * 4]);
#pragma unroll
            for (int i = 0; i < 8; ++i) {
                float a = Mg[(ty * 8 + i) * 128 + k];
                acc[i][0] += a * b4.x; acc[i][1] += a * b4.y; acc[i][2] += a * b4.z; acc[i][3] += a * b4.w;
            }
        }
#pragma unroll
        for (int i = 0; i < 8; ++i)
#pragma unroll
            for (int j = 0; j < 4; ++j)
                Us[ty * 8 + i][tx * 4 + j] = acc[i][j];
    }
    __syncthreads();
    {
        const int l = t & 127, dg = (t >> 7) * 32;
        float acc2[32];
#pragma unroll
        for (int dd = 0; dd < 32; ++dd) acc2[dd] = 0.f;
        const float* kg = k2 + (size_t)bh * 16384;
        for (int j = 0; j < 128; ++j) {
            float kv = kg[j * 128 + l];
#pragma unroll
            for (int dd = 0; dd < 32; ++dd) acc2[dd] += kv * Us[j][dg + dd];
        }
        _Float16* wt = W2T + (size_t)bh * (cHD * cNL);
#pragma unroll
        for (int dd = 0; dd < 32; ++dd)
            wt[(size_t)(dg + dd) * cNL + l] = (_Float16)(acc2[dd] * invc);
    }
}

// ---------------------------------------------------------------------------
// k1_mfma (unchanged)
// ---------------------------------------------------------------------------
__global__ __launch_bounds__(256) void k1_mfma(
    const _Float16* __restrict__ Qh, const _Float16* __restrict__ Klh,
    const _Float16* __restrict__ W2T, _Float16* __restrict__ ctxh)
{
    __shared__ __align__(16) _Float16 Qs[64 * 72];
    __shared__ __align__(16) _Float16 Ps[64 * 136];
    const int s0 = blockIdx.x * 64, bh = blockIdx.y;
    const int b = bh >> 4, h = bh & 15;
    const int t = threadIdx.x;
    const int wave = t >> 6, lane = t & 63;
    const int quad = lane >> 4, l15 = lane & 15;

    {
        const _Float16* qg = Qh + ((size_t)bh * cS + s0) * cHD;
#pragma unroll
        for (int i = 0; i < 2; ++i) {
            int idx = t + i * 256;
            int row = idx >> 3, c8 = idx & 7;
            *reinterpret_cast<f16x8*>(&Qs[row * 72 + c8 * 8]) =
                *reinterpret_cast<const f16x8*>(qg + (size_t)row * cHD + c8 * 8);
        }
    }
    __syncthreads();

    const _Float16* klg = Klh + (size_t)bh * cNL * cHD;
    f32x4 accS[8];
#pragma unroll
    for (int nt = 0; nt < 8; ++nt) accS[nt] = (f32x4){0.f, 0.f, 0.f, 0.f};
#pragma unroll
    for (int k0 = 0; k0 < 2; ++k0) {
        f16x8 aq = *reinterpret_cast<const f16x8*>(&Qs[(wave * 16 + l15) * 72 + k0 * 32 + quad * 8]);
#pragma unroll
        for (int nt = 0; nt < 8; ++nt) {
            f16x8 bk = *reinterpret_cast<const f16x8*>(klg + (size_t)(nt * 16 + l15) * cHD + k0 * 32 + quad * 8);
            accS[nt] = __builtin_amdgcn_mfma_f32_16x16x32_f16(aq, bk, accS[nt], 0, 0, 0);
        }
    }

    float rmax[4] = {-1e30f, -1e30f, -1e30f, -1e30f};
#pragma unroll
    for (int nt = 0; nt < 8; ++nt)
#pragma unroll
        for (int r = 0; r < 4; ++r) rmax[r] = fmaxf(rmax[r], accS[nt][r]);
#pragma unroll
    for (int r = 0; r < 4; ++r)
#pragma unroll
        for (int w = 1; w < 16; w <<= 1) rmax[r] = fmaxf(rmax[r], __shfl_xor(rmax[r], w, 16));
    float rsum[4] = {0.f, 0.f, 0.f, 0.f};
#pragma unroll
    for (int nt = 0; nt < 8; ++nt)
#pragma unroll
        for (int r = 0; r < 4; ++r) { accS[nt][r] = __expf(accS[nt][r] - rmax[r]); rsum[r] += accS[nt][r]; }
#pragma unroll
    for (int r = 0; r < 4; ++r) {
#pragma unroll
        for (int w = 1; w < 16; w <<= 1) rsum[r] += __shfl_xor(rsum[r], w, 16);
        rsum[r] = 1.0f / rsum[r];
    }
#pragma unroll
    for (int nt = 0; nt < 8; ++nt)
#pragma unroll
        for (int r = 0; r < 4; ++r)
            Ps[(wave * 16 + quad * 4 + r) * 136 + nt * 16 + l15] = (_Float16)(accS[nt][r] * rsum[r]);
    __syncthreads();

    const _Float16* wtg = W2T + (size_t)bh * cHD * cNL;
    f32x4 accO[4];
#pragma unroll
    for (int nt = 0; nt < 4; ++nt) accO[nt] = (f32x4){0.f, 0.f, 0.f, 0.f};
#pragma unroll
    for (int k0 = 0; k0 < 4; ++k0) {
        f16x8 ap = *reinterpret_cast<const f16x8*>(&Ps[(wave * 16 + l15) * 136 + k0 * 32 + quad * 8]);
#pragma unroll
        for (int nt = 0; nt < 4; ++nt) {
            f16x8 bw = *reinterpret_cast<const f16x8*>(wtg + (size_t)(nt * 16 + l15) * cNL + k0 * 32 + quad * 8);
            accO[nt] = __builtin_amdgcn_mfma_f32_16x16x32_f16(ap, bw, accO[nt], 0, 0, 0);
        }
    }
#pragma unroll
    for (int nt = 0; nt < 4; ++nt)
#pragma unroll
        for (int r = 0; r < 4; ++r) {
            int s = s0 + wave * 16 + quad * 4 + r;
            int d = nt * 16 + l15;
            ctxh[((size_t)(b * cS) + s) * cD + h * cHD + d] = (_Float16)accO[nt][r];
        }
}

// ---------------------------------------------------------------------------
extern "C" void kernel_launch(void* const* d_in, const int* in_sizes, int n_in,
                              void* d_out, int out_size, void* d_ws, size_t ws_size,
                              hipStream_t stream)
{
    const float* X    = (const float*)d_in[0];
    const float* mask = (const float*)d_in[1];
    const float* Wq   = (const float*)d_in[2];
    const float* bq   = (const float*)d_in[3];
    const float* Wk   = (const float*)d_in[4];
    const float* bk   = (const float*)d_in[5];
    const float* Wv   = (const float*)d_in[6];
    const float* bv   = (const float*)d_in[7];
    const float* Wo   = (const float*)d_in[8];
    const float* bo   = (const float*)d_in[9];
    float* out = (float*)d_out;

    float* ws = (float*)d_ws;
    size_t off = 0;
    const size_t szQKV = (size_t)cBH * cS * cHD;      // 8388608 floats
    const size_t szL   = (size_t)cBH * cNL * cHD;     // 262144
    const size_t szM   = (size_t)cBH * cNL * cNL;     // 524288
    float* Qr   = ws + off; off += szQKV;             // Qh f16 (1st half) | Opart f32 (2nd half)
    float* Kr   = ws + off; off += szQKV;             // Kh f16 (1st half) | ctxh f16 (2nd half)
    float* Vr   = ws + off; off += szQKV;             // Vh f16 (1st half) | VTh f16 (2nd half)
    _Float16* Xh  = (_Float16*)(ws + off); off += szQKV / 2;
    _Float16* WqT = (_Float16*)(ws + off); off += 524288;
    _Float16* WkT = (_Float16*)(ws + off); off += 524288;
    _Float16* WvT = (_Float16*)(ws + off); off += 524288;
    _Float16* WoT = (_Float16*)(ws + off); off += 524288;
    float* Xm   = ws + off; off += (size_t)cB * cNL * cHID;
    float* mbar = ws + off; off += 256;
    float* Ql  = ws + off; off += szL;
    float* Kl  = ws + off; off += szL;
    float* k2  = ws + off; off += szM;
    float* Mg0 = ws + off; off += szM;                // M double-buffer 0
    float* Mg1 = ws + off; off += szM;                // M double-buffer 1
    float* Agb = ws + off; off += szM;                // A-matrix (global, fp32)
    float* T2b = ws + off; off += szM;                // (unused)
    float* T3b = ws + off; off += szM;                // (unused)
    float* CV  = ws + off; off += szL;
    _Float16* Qlh  = (_Float16*)(ws + off); off += szL / 2;
    _Float16* Klh  = (_Float16*)(ws + off); off += szL / 2;
    _Float16* W2Th = (_Float16*)(ws + off); off += szL / 2;
    int*   cmax = (int*)(ws + off); off += 16;
    float* mpart = ws + off; off += 65536;
    float* spart = ws + off; off += 65536;

    _Float16* Qh   = (_Float16*)Qr;
    float*    Opart = Qr + szQKV / 2;        // 2nd half of Q region (Qh untouched)
    _Float16* Kh   = (_Float16*)Kr;
    _Float16* ctxh = (_Float16*)(Kr + szQKV / 2);   // 2nd half of K region
    _Float16* Vh   = (_Float16*)Vr;
    _Float16* VTh  = (_Float16*)(Vr + szQKV / 2);   // 2nd half of V region

    (void)T2b; (void)T3b;

    hipMemsetAsync(cmax, 0, sizeof(int), stream);

    wcast_t<<<dim3(32, 32, 4), 256, 0, stream>>>(Wq, Wk, Wv, Wo, WqT, WkT, WvT, WoT);
    xm_kernel<<<dim3(cB * cNL, 4), 64, 0, stream>>>(X, mask, Xm, mbar, Xh);

    qkv_gemm_f16<<<dim3(512, 1, 3), 256, 0, stream>>>(
        Xh, mask, WqT, WkT, WvT, bq, bk, bv, Qh, Kh, Vh);
    vtrans<<<dim3(cS / 64, cBH), 256, 0, stream>>>(Vh, VTh);
    lgemm<<<dim3(cD / 64, (cB * cNL) / 64, 2), 256, 0, stream>>>(Xm, mbar, Wq, bq, Wk, bk, Ql, Kl, Qlh, Klh);

    k2_softmax<<<cBH * cNL, 128, 0, stream>>>(Ql, Kl, k2);
    colsum_max<<<cBH, 128, 0, stream>>>(k2, cmax);

    // fused: Newton-Schulz (32 blocks) overlapped with k3v flash-prefill (512)
    nys_k3v<<<dim3(32 + 16 * cBH), 512, 0, stream>>>(
        k2, cmax, Agb, Mg0, Mg1, Qlh, Kh, VTh, mask, Opart, mpart, spart);

    k3v_reduce<<<1024, 256, 0, stream>>>(Opart, mpart, spart, CV);
    // W2 = (K^T/c) @ M6 @ CV, applied lazily
    w2_matmul<<<cBH, 256, 0, stream>>>(k2, Mg1, cmax, CV, W2Th);
    k1_mfma<<<dim3(cS / 64, cBH), 256, 0, stream>>>(Qh, Klh, W2Th, ctxh);
    out_gemm_f16<<<dim3(512), 256, 0, stream>>>(ctxh, WoT, bo, out);
}

// Round 10
// 476.471 us; speedup vs baseline: 1.0904x; 1.0904x over previous
//
#include <hip/hip_runtime.h>
#include <math.h>

// Problem constants
constexpr int cB = 2, cS = 4096, cHID = 1024, cNH = 16, cHD = 64, cNL = 128, cSEG = 32, cD = 1024, cBH = 32;
constexpr float cSCALE = 0.35355339059327373f;   // 1/sqrt(sqrt(64))

typedef _Float16 f16x8 __attribute__((ext_vector_type(8)));
typedef float f32x4 __attribute__((ext_vector_type(4)));

__device__ inline void gload_lds16(const void* g, void* l) {
    __builtin_amdgcn_global_load_lds(
        (const __attribute__((address_space(1))) void*)g,
        (__attribute__((address_space(3))) void*)l, 16, 0, 0);
}

// ---------------------------------------------------------------------------
// transpose+cast W (K x N fp32) -> WT (N x K fp16)
// ---------------------------------------------------------------------------
__global__ __launch_bounds__(256) void wcast_t(
    const float* __restrict__ Wq, const float* __restrict__ Wk,
    const float* __restrict__ Wv, const float* __restrict__ Wo,
    _Float16* __restrict__ WqT, _Float16* __restrict__ WkT,
    _Float16* __restrict__ WvT, _Float16* __restrict__ WoT)
{
    __shared__ float tile[32][33];
    const int wsel = blockIdx.z;
    const float* W = (wsel == 0) ? Wq : (wsel == 1 ? Wk : (wsel == 2 ? Wv : Wo));
    _Float16* WT   = (wsel == 0) ? WqT : (wsel == 1 ? WkT : (wsel == 2 ? WvT : WoT));
    const int n0 = blockIdx.x * 32, k0 = blockIdx.y * 32;
    const int t = threadIdx.x;
    const int r = t >> 3, c = (t & 7) * 4;
    float4 v = *reinterpret_cast<const float4*>(W + (size_t)(k0 + r) * cD + n0 + c);
    tile[r][c] = v.x; tile[r][c + 1] = v.y; tile[r][c + 2] = v.z; tile[r][c + 3] = v.w;
    __syncthreads();
    union { _Float16 h[4]; ushort4 u; } p;
    p.h[0] = (_Float16)tile[c + 0][r]; p.h[1] = (_Float16)tile[c + 1][r];
    p.h[2] = (_Float16)tile[c + 2][r]; p.h[3] = (_Float16)tile[c + 3][r];
    *reinterpret_cast<ushort4*>(WT + (size_t)(n0 + r) * cHID + k0 + c) = p.u;
}

// ---------------------------------------------------------------------------
// xm_kernel (+fused cast_x), 4x D-split: grid (256, 4) x 64 thr.
// ---------------------------------------------------------------------------
__global__ __launch_bounds__(64) void xm_kernel(
    const float* __restrict__ X, const float* __restrict__ mask,
    float* __restrict__ Xm, float* __restrict__ mbar, _Float16* __restrict__ Xh)
{
    const int bl = blockIdx.x;          // b*128 + l
    const int q  = blockIdx.y;          // D quarter
    const int b = bl >> 7, l = bl & 127;
    const int c = q * 256 + threadIdx.x * 4;
    float4 a = {0.f, 0.f, 0.f, 0.f};
    float msum = 0.f;
    for (int j = 0; j < cSEG; ++j) {
        float m = mask[b * cS + l * cSEG + j];
        size_t roff = ((size_t)(b * cS + l * cSEG + j)) * cHID + c;
        float4 x = *reinterpret_cast<const float4*>(X + roff);
        union { _Float16 h[4]; ushort4 u; } p;
        p.h[0] = (_Float16)x.x; p.h[1] = (_Float16)x.y;
        p.h[2] = (_Float16)x.z; p.h[3] = (_Float16)x.w;
        *reinterpret_cast<ushort4*>(Xh + roff) = p.u;
        a.x += m * x.x; a.y += m * x.y; a.z += m * x.z; a.w += m * x.w;
        msum += m;
    }
    const float inv = 1.0f / cSEG;
    a.x *= inv; a.y *= inv; a.z *= inv; a.w *= inv;
    *reinterpret_cast<float4*>(Xm + (size_t)bl * cHID + c) = a;
    if (q == 0 && threadIdx.x == 0) mbar[bl] = msum * inv;
}

// ---------------------------------------------------------------------------
// f16 MFMA GEMM: QKV. BK=64, XOR-swizzled LDS, XCD-aware blocks.
// grid: dim3(512, 1, 3)
// ---------------------------------------------------------------------------
__global__ __launch_bounds__(256) void qkv_gemm_f16(
    const _Float16* __restrict__ Xh, const float* __restrict__ mask,
    const _Float16* __restrict__ WqT, const _Float16* __restrict__ WkT, const _Float16* __restrict__ WvT,
    const float* __restrict__ bq, const float* __restrict__ bk, const float* __restrict__ bv,
    _Float16* __restrict__ Qh, _Float16* __restrict__ Kh, _Float16* __restrict__ Vh)
{
    __shared__ __align__(16) _Float16 As[128 * 64];
    __shared__ __align__(16) _Float16 Bs[128 * 64];
    const int wsel = blockIdx.z;
    const _Float16* WT = (wsel == 0) ? WqT : (wsel == 1 ? WkT : WvT);
    const float* bias  = (wsel == 0) ? bq  : (wsel == 1 ? bk  : bv);
    _Float16* Y        = (wsel == 0) ? Qh  : (wsel == 1 ? Kh  : Vh);
    const int orig = blockIdx.x;
    const int xcd = orig & 7, idx = orig >> 3;
    const int n0 = (idx & 7) * 128;
    const int m0 = (xcd * 8 + (idx >> 3)) * 128;
    const int t = threadIdx.x;
    const int wave = t >> 6, lane = t & 63;
    const int wm = (wave >> 1) * 64, wn = (wave & 1) * 64;
    const int quad = lane >> 4, l15 = lane & 15;
    const int srow = wave * 8 + (lane >> 3);
    const int scol = ((lane & 7) ^ (lane >> 3)) * 8;

    f32x4 acc[4][4];
#pragma unroll
    for (int i = 0; i < 4; ++i)
#pragma unroll
        for (int j = 0; j < 4; ++j) acc[i][j] = (f32x4){0.f, 0.f, 0.f, 0.f};

    for (int k0 = 0; k0 < cHID; k0 += 64) {
        const _Float16* aSrc = Xh + (size_t)(m0 + srow) * cHID + k0 + scol;
        const _Float16* bSrc = WT + (size_t)(n0 + srow) * cHID + k0 + scol;
#pragma unroll
        for (int i = 0; i < 4; ++i) {
            gload_lds16(aSrc + (size_t)(i * 32) * cHID, &As[(wave * 8 + i * 32) * 64]);
            gload_lds16(bSrc + (size_t)(i * 32) * cHID, &Bs[(wave * 8 + i * 32) * 64]);
        }
        __syncthreads();
        f16x8 af[2][4], bf[2][4];
#pragma unroll
        for (int kh = 0; kh < 2; ++kh) {
            const int cg = ((kh * 4 + quad) ^ (l15 & 7)) * 8;
#pragma unroll
            for (int mt = 0; mt < 4; ++mt)
                af[kh][mt] = *reinterpret_cast<const f16x8*>(&As[(wm + mt * 16 + l15) * 64 + cg]);
#pragma unroll
            for (int nt = 0; nt < 4; ++nt)
                bf[kh][nt] = *reinterpret_cast<const f16x8*>(&Bs[(wn + nt * 16 + l15) * 64 + cg]);
        }
#pragma unroll
        for (int kh = 0; kh < 2; ++kh)
#pragma unroll
            for (int mt = 0; mt < 4; ++mt)
#pragma unroll
                for (int nt = 0; nt < 4; ++nt)
                    acc[mt][nt] = __builtin_amdgcn_mfma_f32_16x16x32_f16(af[kh][mt], bf[kh][nt], acc[mt][nt], 0, 0, 0);
        __syncthreads();
    }
#pragma unroll
    for (int mt = 0; mt < 4; ++mt) {
#pragma unroll
        for (int r = 0; r < 4; ++r) {
            int R = m0 + wm + mt * 16 + quad * 4 + r;
            int b = R >> 12, s = R & (cS - 1);
            float msc = (wsel < 2) ? mask[b * cS + s] * cSCALE : 1.0f;
#pragma unroll
            for (int nt = 0; nt < 4; ++nt) {
                int Cc = n0 + wn + nt * 16 + l15;
                int h = Cc >> 6, d = Cc & 63;
                float val = (acc[mt][nt][r] + bias[Cc]) * msc;
                Y[((size_t)(b * cNH + h) * cS + s) * cHD + d] = (_Float16)val;
            }
        }
    }
}

// ---------------------------------------------------------------------------
// f16 MFMA GEMM: out = ctxh @ Wo + bo  (BK=64, swizzled, XCD-aware), grid 512
// ---------------------------------------------------------------------------
__global__ __launch_bounds__(256) void out_gemm_f16(
    const _Float16* __restrict__ Ah, const _Float16* __restrict__ WT,
    const float* __restrict__ bias, float* __restrict__ Y)
{
    __shared__ __align__(16) _Float16 As[128 * 64];
    __shared__ __align__(16) _Float16 Bs[128 * 64];
    const int orig = blockIdx.x;
    const int xcd = orig & 7, idx = orig >> 3;
    const int n0 = (idx & 7) * 128;
    const int m0 = (xcd * 8 + (idx >> 3)) * 128;
    const int t = threadIdx.x;
    const int wave = t >> 6, lane = t & 63;
    const int wm = (wave >> 1) * 64, wn = (wave & 1) * 64;
    const int quad = lane >> 4, l15 = lane & 15;
    const int srow = wave * 8 + (lane >> 3);
    const int scol = ((lane & 7) ^ (lane >> 3)) * 8;

    f32x4 acc[4][4];
#pragma unroll
    for (int i = 0; i < 4; ++i)
#pragma unroll
        for (int j = 0; j < 4; ++j) acc[i][j] = (f32x4){0.f, 0.f, 0.f, 0.f};

    for (int k0 = 0; k0 < cD; k0 += 64) {
        const _Float16* aSrc = Ah + (size_t)(m0 + srow) * cD + k0 + scol;
        const _Float16* bSrc = WT + (size_t)(n0 + srow) * cD + k0 + scol;
#pragma unroll
        for (int i = 0; i < 4; ++i) {
            gload_lds16(aSrc + (size_t)(i * 32) * cD, &As[(wave * 8 + i * 32) * 64]);
            gload_lds16(bSrc + (size_t)(i * 32) * cD, &Bs[(wave * 8 + i * 32) * 64]);
        }
        __syncthreads();
        f16x8 af[2][4], bf[2][4];
#pragma unroll
        for (int kh = 0; kh < 2; ++kh) {
            const int cg = ((kh * 4 + quad) ^ (l15 & 7)) * 8;
#pragma unroll
            for (int mt = 0; mt < 4; ++mt)
                af[kh][mt] = *reinterpret_cast<const f16x8*>(&As[(wm + mt * 16 + l15) * 64 + cg]);
#pragma unroll
            for (int nt = 0; nt < 4; ++nt)
                bf[kh][nt] = *reinterpret_cast<const f16x8*>(&Bs[(wn + nt * 16 + l15) * 64 + cg]);
        }
#pragma unroll
        for (int kh = 0; kh < 2; ++kh)
#pragma unroll
            for (int mt = 0; mt < 4; ++mt)
#pragma unroll
                for (int nt = 0; nt < 4; ++nt)
                    acc[mt][nt] = __builtin_amdgcn_mfma_f32_16x16x32_f16(af[kh][mt], bf[kh][nt], acc[mt][nt], 0, 0, 0);
        __syncthreads();
    }
#pragma unroll
    for (int mt = 0; mt < 4; ++mt) {
#pragma unroll
        for (int r = 0; r < 4; ++r) {
            int R = m0 + wm + mt * 16 + quad * 4 + r;
#pragma unroll
            for (int nt = 0; nt < 4; ++nt) {
                int Cc = n0 + wn + nt * 16 + l15;
                Y[(size_t)R * cHID + Cc] = acc[mt][nt][r] + bias[Cc];
            }
        }
    }
}

// ---------------------------------------------------------------------------
// Landmark GEMM (fp32, exact path). Emits f16 Qlh/Klh for MFMA consumers.
// ---------------------------------------------------------------------------
__global__ __launch_bounds__(256) void lgemm(
    const float* __restrict__ Xm, const float* __restrict__ mbar,
    const float* __restrict__ Wq, const float* __restrict__ bq,
    const float* __restrict__ Wk, const float* __restrict__ bk,
    float* __restrict__ Ql, float* __restrict__ Kl,
    _Float16* __restrict__ Qlh, _Float16* __restrict__ Klh)
{
    __shared__ __align__(16) float As[16][68];
    __shared__ __align__(16) float Bs[16][68];
    const int tid = threadIdx.x;
    const int wsel = blockIdx.z;
    const float* W    = wsel ? Wk : Wq;
    const float* bias = wsel ? bk : bq;
    float* Yl         = wsel ? Kl : Ql;
    _Float16* Ylh     = wsel ? Klh : Qlh;
    const int c0 = blockIdx.x * 64, r0 = blockIdx.y * 64;
    const int tx = tid & 15, ty = tid >> 4;
    const int am = tid >> 2, ak = (tid & 3) * 4;
    const int bkk = tid >> 4, bn = (tid & 15) * 4;

    float acc[4][4] = {};
    for (int k0 = 0; k0 < cHID; k0 += 16) {
        float4 a4 = *reinterpret_cast<const float4*>(Xm + (size_t)(r0 + am) * cHID + k0 + ak);
        As[ak + 0][am] = a4.x; As[ak + 1][am] = a4.y; As[ak + 2][am] = a4.z; As[ak + 3][am] = a4.w;
        float4 b4 = *reinterpret_cast<const float4*>(W + (size_t)(k0 + bkk) * cD + c0 + bn);
        *reinterpret_cast<float4*>(&Bs[bkk][bn]) = b4;
        __syncthreads();
#pragma unroll
        for (int kk = 0; kk < 16; ++kk) {
            float4 av  = *reinterpret_cast<const float4*>(&As[kk][ty * 4]);
            float4 bv4 = *reinterpret_cast<const float4*>(&Bs[kk][tx * 4]);
            float a_[4] = {av.x, av.y, av.z, av.w};
            float b_[4] = {bv4.x, bv4.y, bv4.z, bv4.w};
#pragma unroll
            for (int i = 0; i < 4; ++i)
#pragma unroll
                for (int j = 0; j < 4; ++j) acc[i][j] += a_[i] * b_[j];
        }
        __syncthreads();
    }
#pragma unroll
    for (int i = 0; i < 4; ++i) {
        int r = r0 + ty * 4 + i;          // b*128 + l
        int b = r >> 7, l = r & 127;
        float mb = mbar[r];
#pragma unroll
        for (int j = 0; j < 4; ++j) {
            int c = c0 + tx * 4 + j;
            int h = c >> 6, d = c & 63;
            float val = (acc[i][j] + mb * bias[c]) * cSCALE;
            size_t idx = ((size_t)(b * cNH + h) * cNL + l) * cHD + d;
            Yl[idx] = val;
            Ylh[idx] = (_Float16)val;
        }
    }
}

// ---------------------------------------------------------------------------
// k2 softmax chain (fp32-clean path)
// ---------------------------------------------------------------------------
__global__ __launch_bounds__(128) void k2_softmax(
    const float* __restrict__ Ql, const float* __restrict__ Kl, float* __restrict__ k2)
{
    __shared__ __align__(16) float qrow[64];
    __shared__ float red[128];
    int bh = blockIdx.x >> 7, i = blockIdx.x & 127;
    int j = threadIdx.x;
    if (j < 64) qrow[j] = Ql[(bh * cNL + i) * cHD + j];
    __syncthreads();
    const float4* q4  = reinterpret_cast<const float4*>(qrow);
    const float4* kl4 = reinterpret_cast<const float4*>(Kl + (bh * cNL + j) * cHD);
    float dot = 0.f;
#pragma unroll
    for (int u = 0; u < 16; ++u) {
        float4 a = q4[u], b = kl4[u];
        dot += a.x * b.x + a.y * b.y + a.z * b.z + a.w * b.w;
    }
    red[j] = dot; __syncthreads();
    for (int off = 64; off > 0; off >>= 1) { if (j < off) red[j] = fmaxf(red[j], red[j + off]); __syncthreads(); }
    float m = red[0]; __syncthreads();
    float e = expf(dot - m);
    red[j] = e; __syncthreads();
    for (int off = 64; off > 0; off >>= 1) { if (j < off) red[j] += red[j + off]; __syncthreads(); }
    k2[(bh * cNL + i) * cNL + j] = e / red[0];
}

__global__ __launch_bounds__(128) void colsum_max(const float* __restrict__ k2, int* __restrict__ cmax)
{
    __shared__ float red[128];
    int bh = blockIdx.x, j = threadIdx.x;
    float s = 0.f;
    for (int i = 0; i < cNL; ++i) s += k2[(bh * cNL + i) * cNL + j];
    red[j] = s; __syncthreads();
    for (int off = 64; off > 0; off >>= 1) { if (j < off) red[j] = fmaxf(red[j], red[j + off]); __syncthreads(); }
    if (j == 0) atomicMax(cmax, __float_as_int(red[0]));
}

// ---------------------------------------------------------------------------
// Helpers for fused nys+k3v
// ---------------------------------------------------------------------------
__device__ inline void split2(float v, _Float16& h, _Float16& l) {
    h = (_Float16)v;
    l = (_Float16)(v - (float)h);
}
__device__ inline unsigned short f16bits(_Float16 h) { return __builtin_bit_cast(unsigned short, h); }

#define NYS_MFMA(a, b, c) __builtin_amdgcn_mfma_f32_16x16x32_f16((a), (b), (c), 0, 0, 0)

// preload left frags: rows wr*64 + mt*16 + l15 (mt 0..3), contiguous b128
#define NYS_PRELOAD(PH, PL, LH, LL)                                                     \
    {                                                                                   \
        _Pragma("unroll")                                                               \
        for (int mt_ = 0; mt_ < 4; ++mt_) {                                             \
            const int rowL_ = wr * 64 + mt_ * 16 + l15;                                 \
            _Pragma("unroll")                                                           \
            for (int k0_ = 0; k0_ < 4; ++k0_) {                                         \
                LH[mt_][k0_] = *reinterpret_cast<const f16x8*>(&PH[rowL_ * 136 + k0_ * 32 + quad * 8]); \
                LL[mt_][k0_] = *reinterpret_cast<const f16x8*>(&PL[rowL_ * 136 + k0_ * 32 + quad * 8]); \
            }                                                                           \
        }                                                                               \
    }

// product over wave's 64x32 region; 3-term split (HH + LH + HL)
#define NYS_PRODUCT(PH, PL, LH, LL)                                                     \
    {                                                                                   \
        _Pragma("unroll")                                                               \
        for (int mt_ = 0; mt_ < 4; ++mt_)                                               \
            _Pragma("unroll")                                                           \
            for (int nt_ = 0; nt_ < 2; ++nt_) acc[mt_][nt_] = (f32x4){0.f, 0.f, 0.f, 0.f}; \
        _Pragma("unroll")                                                               \
        for (int nt_ = 0; nt_ < 2; ++nt_) {                                             \
            _Pragma("unroll")                                                           \
            for (int k0_ = 0; k0_ < 4; ++k0_) {                                         \
                const int boff_ = (wcb + nt_ * 16) * 136 + k0_ * 32 + quad * 8;         \
                f16x8 bh_ = *reinterpret_cast<const f16x8*>(&PH[boff_]);                \
                f16x8 bl_ = *reinterpret_cast<const f16x8*>(&PL[boff_]);                \
                _Pragma("unroll")                                                       \
                for (int mt_ = 0; mt_ < 4; ++mt_) {                                     \
                    acc[mt_][nt_] = NYS_MFMA(LH[mt_][k0_], bh_, acc[mt_][nt_]);         \
                    acc[mt_][nt_] = NYS_MFMA(LL[mt_][k0_], bh_, acc[mt_][nt_]);         \
                    acc[mt_][nt_] = NYS_MFMA(LH[mt_][k0_], bl_, acc[mt_][nt_]);         \
                }                                                                       \
            }                                                                           \
        }                                                                               \
    }

// ---------------------------------------------------------------------------
// nys_k3v v2: blocks [0,32) run the R8-verified Newton-Schulz (A+W planes in
// 136KB LDS, 8 waves, M-chain in global fp32). Blocks [32,288) run the
// barrier-free k3v flash-prefill with 8 waves = 2 chunks/block (wave-group
// 0/1 owns chunk and 18KB Ps slice). 136KB LDS -> 1 block/CU; nys owns 32
// CUs at full R8 speed while k3v's 512 chunks fill the remaining CUs.
// ---------------------------------------------------------------------------
__global__ __launch_bounds__(512, 2) void nys_k3v(
    const float* __restrict__ k2, const int* __restrict__ cmax,
    float* __restrict__ Mg0, float* __restrict__ Mg1,
    const _Float16* __restrict__ Qlh, const _Float16* __restrict__ Kh,
    const _Float16* __restrict__ VTh, const float* __restrict__ mask,
    float* __restrict__ Opart, float* __restrict__ mpart, float* __restrict__ spart)
{
    __shared__ __align__(16) _Float16 SMEM[4 * 128 * 136];   // 136 KB

    if (blockIdx.x < 32) {
        // ================= NYS role (R8 v5, unchanged) =================
        _Float16* Ahi_s = SMEM;
        _Float16* Alo_s = SMEM + 128 * 136;
        _Float16* Whi_s = SMEM + 2 * 128 * 136;
        _Float16* Wlo_s = SMEM + 3 * 128 * 136;
        const int bh = blockIdx.x;
        const int t = threadIdx.x;
        const int wave = t >> 6, lane = t & 63;
        const int wr = wave >> 2, wc = wave & 3;          // 2 row-groups x 4 col-groups
        const int quad = lane >> 4, l15 = lane & 15;
        const int wcb = wc * 32 + l15;
        const float* Kg = k2 + (size_t)bh * 16384;
        float* Mg0b = Mg0 + (size_t)bh * 16384;
        float* Mg1b = Mg1 + (size_t)bh * 16384;
        const float sc = sqrtf(1.0f / __int_as_float(*cmax));

        // stage Kp = K*sqrt(1/c) into W planes
        {
            const int row = t >> 2, c0 = (t & 3) * 32;
            const float* src = Kg + row * 128 + c0;
            _Float16* dh = &Whi_s[row * 136 + c0];
            _Float16* dl = &Wlo_s[row * 136 + c0];
#pragma unroll
            for (int u = 0; u < 32; u += 4) {
                float4 v = *reinterpret_cast<const float4*>(src + u);
                ushort4 ph, pl; _Float16 h, l;
                split2(v.x * sc, h, l); ph.x = f16bits(h); pl.x = f16bits(l);
                split2(v.y * sc, h, l); ph.y = f16bits(h); pl.y = f16bits(l);
                split2(v.z * sc, h, l); ph.z = f16bits(h); pl.z = f16bits(l);
                split2(v.w * sc, h, l); ph.w = f16bits(h); pl.w = f16bits(l);
                *reinterpret_cast<ushort4*>(dh + u) = ph;
                *reinterpret_cast<ushort4*>(dl + u) = pl;
            }
        }
        __syncthreads();

        f32x4 acc[4][2];
        f16x8 Fh[4][4], Fl[4][4];

        // A1 = Kp @ Kp^T -> A planes
        NYS_PRELOAD(Whi_s, Wlo_s, Fh, Fl);
        NYS_PRODUCT(Whi_s, Wlo_s, Fh, Fl);
#pragma unroll
        for (int mt = 0; mt < 4; ++mt)
#pragma unroll
            for (int nt = 0; nt < 2; ++nt) {
                const int col = wcb + nt * 16;
                const int rb  = wr * 64 + mt * 16 + quad * 4;
                ushort4 ph, pl;
#pragma unroll
                for (int r = 0; r < 4; ++r) {
                    _Float16 h, l; split2(acc[mt][nt][r], h, l);
                    ((unsigned short*)&ph)[r] = f16bits(h);
                    ((unsigned short*)&pl)[r] = f16bits(l);
                }
                *reinterpret_cast<ushort4*>(&Ahi_s[col * 136 + rb]) = ph;
                *reinterpret_cast<ushort4*>(&Alo_s[col * 136 + rb]) = pl;
            }
        __syncthreads();

        for (int it = 0; it < 6; ++it) {
            NYS_PRELOAD(Ahi_s, Alo_s, Fh, Fl);
            // Z = A @ A
            NYS_PRODUCT(Ahi_s, Alo_s, Fh, Fl);
            // B2 = 15I - 7A + Z -> W planes
#pragma unroll
            for (int mt = 0; mt < 4; ++mt)
#pragma unroll
                for (int nt = 0; nt < 2; ++nt) {
                    const int col = wcb + nt * 16;
                    const int rb  = wr * 64 + mt * 16 + quad * 4;
                    ushort4 ah = *reinterpret_cast<const ushort4*>(&Ahi_s[col * 136 + rb]);
                    ushort4 al = *reinterpret_cast<const ushort4*>(&Alo_s[col * 136 + rb]);
                    ushort4 ph, pl;
#pragma unroll
                    for (int r = 0; r < 4; ++r) {
                        float av = (float)__builtin_bit_cast(_Float16, ((unsigned short*)&ah)[r])
                                 + (float)__builtin_bit_cast(_Float16, ((unsigned short*)&al)[r]);
                        float v = ((rb + r) == col ? 15.0f : 0.0f) - 7.0f * av + acc[mt][nt][r];
                        _Float16 h, l; split2(v, h, l);
                        ((unsigned short*)&ph)[r] = f16bits(h);
                        ((unsigned short*)&pl)[r] = f16bits(l);
                    }
                    *reinterpret_cast<ushort4*>(&Whi_s[col * 136 + rb]) = ph;
                    *reinterpret_cast<ushort4*>(&Wlo_s[col * 136 + rb]) = pl;
                }
            __syncthreads();                       // #1: B2 visible
            // P3 = A @ B2
            NYS_PRODUCT(Whi_s, Wlo_s, Fh, Fl);
            __syncthreads();                       // #2: B2 reads done
            // B3 = 13I - P3 -> W planes; it0: M1 = 0.25*B3 -> Mg0
#pragma unroll
            for (int mt = 0; mt < 4; ++mt)
#pragma unroll
                for (int nt = 0; nt < 2; ++nt) {
                    const int col = wcb + nt * 16;
                    const int rb  = wr * 64 + mt * 16 + quad * 4;
                    ushort4 ph, pl; float4 mv;
#pragma unroll
                    for (int r = 0; r < 4; ++r) {
                        float v = ((rb + r) == col ? 13.0f : 0.0f) - acc[mt][nt][r];
                        _Float16 h, l; split2(v, h, l);
                        ((unsigned short*)&ph)[r] = f16bits(h);
                        ((unsigned short*)&pl)[r] = f16bits(l);
                        ((float*)&mv)[r] = 0.25f * v;
                    }
                    *reinterpret_cast<ushort4*>(&Whi_s[col * 136 + rb]) = ph;
                    *reinterpret_cast<ushort4*>(&Wlo_s[col * 136 + rb]) = pl;
                    if (it == 0)
                        *reinterpret_cast<float4*>(&Mg0b[col * 128 + rb]) = mv;
                }
            __syncthreads();                       // #3: B3 visible
            // A4 = A @ B3
            NYS_PRODUCT(Whi_s, Wlo_s, Fh, Fl);
            // A' = 0.25*A4 -> A planes
#pragma unroll
            for (int mt = 0; mt < 4; ++mt)
#pragma unroll
                for (int nt = 0; nt < 2; ++nt) {
                    const int col = wcb + nt * 16;
                    const int rb  = wr * 64 + mt * 16 + quad * 4;
                    ushort4 ph, pl;
#pragma unroll
                    for (int r = 0; r < 4; ++r) {
                        _Float16 h, l; split2(0.25f * acc[mt][nt][r], h, l);
                        ((unsigned short*)&ph)[r] = f16bits(h);
                        ((unsigned short*)&pl)[r] = f16bits(l);
                    }
                    *reinterpret_cast<ushort4*>(&Ahi_s[col * 136 + rb]) = ph;
                    *reinterpret_cast<ushort4*>(&Alo_s[col * 136 + rb]) = pl;
                }
            // M' = 0.25 * M @ B3 (global fp32 double-buffer; k0-sliced frags)
            if (it >= 1) {
                const float* Mr = (it & 1) ? Mg0b : Mg1b;
                float*       Mw = (it & 1) ? Mg1b : Mg0b;
#pragma unroll
                for (int mt = 0; mt < 4; ++mt)
#pragma unroll
                    for (int nt = 0; nt < 2; ++nt) acc[mt][nt] = (f32x4){0.f, 0.f, 0.f, 0.f};
#pragma unroll
                for (int k0 = 0; k0 < 4; ++k0) {
                    f16x8 Mh[4], Ml[4];
#pragma unroll
                    for (int mt = 0; mt < 4; ++mt) {
                        const int rowL = wr * 64 + mt * 16 + l15;
                        const float* src = Mr + rowL * 128 + k0 * 32 + quad * 8;
                        float4 v0 = *reinterpret_cast<const float4*>(src);
                        float4 v1 = *reinterpret_cast<const float4*>(src + 4);
                        union { f16x8 v; _Float16 e[8]; } hh, ll;
                        split2(v0.x, hh.e[0], ll.e[0]); split2(v0.y, hh.e[1], ll.e[1]);
                        split2(v0.z, hh.e[2], ll.e[2]); split2(v0.w, hh.e[3], ll.e[3]);
                        split2(v1.x, hh.e[4], ll.e[4]); split2(v1.y, hh.e[5], ll.e[5]);
                        split2(v1.z, hh.e[6], ll.e[6]); split2(v1.w, hh.e[7], ll.e[7]);
                        Mh[mt] = hh.v; Ml[mt] = ll.v;
                    }
#pragma unroll
                    for (int nt = 0; nt < 2; ++nt) {
                        const int boff = (wcb + nt * 16) * 136 + k0 * 32 + quad * 8;
                        f16x8 bh_ = *reinterpret_cast<const f16x8*>(&Whi_s[boff]);
                        f16x8 bl_ = *reinterpret_cast<const f16x8*>(&Wlo_s[boff]);
#pragma unroll
                        for (int mt = 0; mt < 4; ++mt) {
                            acc[mt][nt] = NYS_MFMA(Mh[mt], bh_, acc[mt][nt]);
                            acc[mt][nt] = NYS_MFMA(Ml[mt], bh_, acc[mt][nt]);
                            acc[mt][nt] = NYS_MFMA(Mh[mt], bl_, acc[mt][nt]);
                        }
                    }
                }
#pragma unroll
                for (int mt = 0; mt < 4; ++mt)
#pragma unroll
                    for (int nt = 0; nt < 2; ++nt) {
                        const int col = wcb + nt * 16;
                        const int rb  = wr * 64 + mt * 16 + quad * 4;
                        float4 mv;
#pragma unroll
                        for (int r = 0; r < 4; ++r) ((float*)&mv)[r] = 0.25f * acc[mt][nt][r];
                        *reinterpret_cast<float4*>(&Mw[col * 128 + rb]) = mv;
                    }
            }
            __syncthreads();                       // #4: A'/M' visible; W free
        }
        // M6 ends in Mg1 (it5 writes Mg1).
    } else {
        // ========== K3V role (barrier-free, 8 waves = 2 chunks) ==========
        const int t = threadIdx.x;
        const int wave8 = t >> 6;                  // 0..7
        const int wg = wave8 >> 2;                 // chunk group 0/1
        const int wave = wave8 & 3;                // wave within group
        _Float16* Ps = SMEM + (size_t)wg * (128 * 72);
        const int zz = (blockIdx.x - 32) * 2 + wg; // 0..511
        const int z = zz & 15, bh = zz >> 4;
        const int b = bh >> 4;
        const int sbase = z * 256;
        const int lane = t & 63;
        const int quad = lane >> 4, l15 = lane & 15;

        f16x8 aq[2][2];
        const _Float16* qlg = Qlh + (size_t)bh * cNL * cHD;
#pragma unroll
        for (int mt = 0; mt < 2; ++mt)
#pragma unroll
            for (int k0 = 0; k0 < 2; ++k0)
                aq[mt][k0] = *reinterpret_cast<const f16x8*>(
                    qlg + (size_t)(wave * 32 + mt * 16 + l15) * cHD + k0 * 32 + quad * 8);

        float mrun[2][4], srun[2][4];
        f32x4 accO[2][4];
#pragma unroll
        for (int mt = 0; mt < 2; ++mt)
#pragma unroll
            for (int r = 0; r < 4; ++r) { mrun[mt][r] = -1e30f; srun[mt][r] = 0.f; }
#pragma unroll
        for (int mt = 0; mt < 2; ++mt)
#pragma unroll
            for (int dt = 0; dt < 4; ++dt) accO[mt][dt] = (f32x4){0.f, 0.f, 0.f, 0.f};

        const _Float16* kg = Kh + (size_t)bh * cS * cHD;
        const _Float16* vg = VTh + (size_t)bh * cHD * cS;

        for (int step = 0; step < 4; ++step) {
            const int st = sbase + step * 64;
            f32x4 accS[2][4];
#pragma unroll
            for (int mt = 0; mt < 2; ++mt)
#pragma unroll
                for (int nt = 0; nt < 4; ++nt) accS[mt][nt] = (f32x4){0.f, 0.f, 0.f, 0.f};
#pragma unroll
            for (int k0 = 0; k0 < 2; ++k0)
#pragma unroll
                for (int nt = 0; nt < 4; ++nt) {
                    f16x8 bk = *reinterpret_cast<const f16x8*>(
                        kg + (size_t)(st + nt * 16 + l15) * cHD + k0 * 32 + quad * 8);
#pragma unroll
                    for (int mt = 0; mt < 2; ++mt)
                        accS[mt][nt] = __builtin_amdgcn_mfma_f32_16x16x32_f16(aq[mt][k0], bk, accS[mt][nt], 0, 0, 0);
                }
#pragma unroll
            for (int nt = 0; nt < 4; ++nt) {
                float pen = 1e9f * (1.0f - mask[b * cS + st + nt * 16 + l15]);
#pragma unroll
                for (int mt = 0; mt < 2; ++mt)
#pragma unroll
                    for (int r = 0; r < 4; ++r) accS[mt][nt][r] -= pen;
            }
#pragma unroll
            for (int mt = 0; mt < 2; ++mt) {
#pragma unroll
                for (int r = 0; r < 4; ++r) {
                    float tmax = fmaxf(fmaxf(accS[mt][0][r], accS[mt][1][r]),
                                       fmaxf(accS[mt][2][r], accS[mt][3][r]));
#pragma unroll
                    for (int w = 1; w < 16; w <<= 1) tmax = fmaxf(tmax, __shfl_xor(tmax, w, 16));
                    float mnew = fmaxf(mrun[mt][r], tmax);
                    float alpha = __expf(mrun[mt][r] - mnew);
                    float ts = 0.f;
#pragma unroll
                    for (int nt = 0; nt < 4; ++nt) {
                        float e = __expf(accS[mt][nt][r] - mnew);
                        accS[mt][nt][r] = e; ts += e;
                    }
#pragma unroll
                    for (int w = 1; w < 16; w <<= 1) ts += __shfl_xor(ts, w, 16);
                    srun[mt][r] = srun[mt][r] * alpha + ts;
                    mrun[mt][r] = mnew;
#pragma unroll
                    for (int dt = 0; dt < 4; ++dt) accO[mt][dt][r] *= alpha;
                }
            }
#pragma unroll
            for (int mt = 0; mt < 2; ++mt)
#pragma unroll
                for (int nt = 0; nt < 4; ++nt)
#pragma unroll
                    for (int r = 0; r < 4; ++r)
                        Ps[(wave * 32 + mt * 16 + quad * 4 + r) * 72 + nt * 16 + l15] =
                            (_Float16)accS[mt][nt][r];
#pragma unroll
            for (int k0 = 0; k0 < 2; ++k0) {
                f16x8 ap[2];
#pragma unroll
                for (int mt = 0; mt < 2; ++mt)
                    ap[mt] = *reinterpret_cast<const f16x8*>(
                        &Ps[(wave * 32 + mt * 16 + l15) * 72 + k0 * 32 + quad * 8]);
#pragma unroll
                for (int dt = 0; dt < 4; ++dt) {
                    f16x8 bv = *reinterpret_cast<const f16x8*>(
                        vg + (size_t)(dt * 16 + l15) * cS + st + k0 * 32 + quad * 8);
#pragma unroll
                    for (int mt = 0; mt < 2; ++mt)
                        accO[mt][dt] = __builtin_amdgcn_mfma_f32_16x16x32_f16(ap[mt], bv, accO[mt][dt], 0, 0, 0);
                }
            }
        }
        const int rowbase = bh * cNL + wave * 32;
#pragma unroll
        for (int mt = 0; mt < 2; ++mt)
#pragma unroll
            for (int dt = 0; dt < 4; ++dt)
#pragma unroll
                for (int r = 0; r < 4; ++r)
                    Opart[(size_t)(z * 4096 + rowbase + mt * 16 + quad * 4 + r) * cHD + dt * 16 + l15] =
                        accO[mt][dt][r];
        if (l15 == 0) {
#pragma unroll
            for (int mt = 0; mt < 2; ++mt)
#pragma unroll
                for (int r = 0; r < 4; ++r) {
                    int prow = z * 4096 + rowbase + mt * 16 + quad * 4 + r;
                    mpart[prow] = mrun[mt][r];
                    spart[prow] = srun[mt][r];
                }
        }
    }
}

// ---------------------------------------------------------------------------
// vtrans: Vh[bh][s][d] f16 -> VTh[bh][d][s] f16 (64x64 LDS tiles)
// ---------------------------------------------------------------------------
__global__ __launch_bounds__(256) void vtrans(const _Float16* __restrict__ Vh, _Float16* __restrict__ VTh)
{
    __shared__ ushort T[64][72];
    const int s0 = blockIdx.x * 64, bh = blockIdx.y;
    const int t = threadIdx.x;
    const _Float16* vb = Vh + ((size_t)bh * cS + s0) * cHD;
#pragma unroll
    for (int i = 0; i < 2; ++i) {
        int idx = t + i * 256;
        int row = idx >> 3, c8 = idx & 7;
        f16x8 v = *reinterpret_cast<const f16x8*>(vb + (size_t)row * cHD + c8 * 8);
#pragma unroll
        for (int j = 0; j < 8; ++j) T[row][c8 * 8 + j] = ((ushort*)&v)[j];
    }
    __syncthreads();
    _Float16* vt = VTh + (size_t)bh * cHD * cS;
#pragma unroll
    for (int i = 0; i < 2; ++i) {
        int idx = t + i * 256;
        int d = idx >> 3, s8 = idx & 7;
        f16x8 o;
#pragma unroll
        for (int j = 0; j < 8; ++j) ((ushort*)&o)[j] = T[s8 * 8 + j][d];
        *reinterpret_cast<f16x8*>(vt + (size_t)d * cS + s0 + s8 * 8) = o;
    }
}

// ---------------------------------------------------------------------------
// w2_matmul (+fused k3v_reduce): reduce 16 chunk partials into CVs (LDS),
// then U = M6 @ CV, then W2T[d][l] = (1/c) * sum_j k2[j][l] * U[j][d]
// ---------------------------------------------------------------------------
__global__ __launch_bounds__(256) void w2_matmul(
    const float* __restrict__ k2, const float* __restrict__ M6,
    const int* __restrict__ cmax,
    const float* __restrict__ Opart, const float* __restrict__ mpart,
    const float* __restrict__ spart,
    _Float16* __restrict__ W2T)
{
    __shared__ __align__(16) float CVs[128][68];
    __shared__ __align__(16) float Us[128][68];
    const int bh = blockIdx.x, t = threadIdx.x;
    const float invc = 1.0f / __int_as_float(*cmax);
    // phase 0: online-softmax combine of the 16 chunk partials
    for (int it = 0; it < 32; ++it) {
        int idx = t + it * 256;            // row*64 + d over 128x64
        int row = idx >> 6, d = idx & 63;
        int grow = bh * cNL + row;
        float mstar = -1e30f;
#pragma unroll
        for (int z = 0; z < 16; ++z) mstar = fmaxf(mstar, mpart[z * 4096 + grow]);
        float ssum = 0.f, acc = 0.f;
#pragma unroll
        for (int z = 0; z < 16; ++z) {
            float w = __expf(mpart[z * 4096 + grow] - mstar);
            ssum += w * spart[z * 4096 + grow];
            acc  += w * Opart[(size_t)(z * 4096 + grow) * cHD + d];
        }
        CVs[row][d] = acc / ssum;
    }
    __syncthreads();
    const float* Mg = M6 + (size_t)bh * 16384;
    {
        const int tx = t & 15, ty = t >> 4;
        float acc[8][4] = {};
        for (int k = 0; k < 128; ++k) {
            float4 b4 = *reinterpret_cast<const float4*>(&CVs[k][tx * 4]);
#pragma unroll
            for (int i = 0; i < 8; ++i) {
                float a = Mg[(ty * 8 + i) * 128 + k];
                acc[i][0] += a * b4.x; acc[i][1] += a * b4.y; acc[i][2] += a * b4.z; acc[i][3] += a * b4.w;
            }
        }
#pragma unroll
        for (int i = 0; i < 8; ++i)
#pragma unroll
            for (int j = 0; j < 4; ++j)
                Us[ty * 8 + i][tx * 4 + j] = acc[i][j];
    }
    __syncthreads();
    {
        const int l = t & 127, dg = (t >> 7) * 32;
        float acc2[32];
#pragma unroll
        for (int dd = 0; dd < 32; ++dd) acc2[dd] = 0.f;
        const float* kg = k2 + (size_t)bh * 16384;
        for (int j = 0; j < 128; ++j) {
            float kv = kg[j * 128 + l];
#pragma unroll
            for (int dd = 0; dd < 32; ++dd) acc2[dd] += kv * Us[j][dg + dd];
        }
        _Float16* wt = W2T + (size_t)bh * (cHD * cNL);
#pragma unroll
        for (int dd = 0; dd < 32; ++dd)
            wt[(size_t)(dg + dd) * cNL + l] = (_Float16)(acc2[dd] * invc);
    }
}

// ---------------------------------------------------------------------------
// k1_mfma (unchanged)
// ---------------------------------------------------------------------------
__global__ __launch_bounds__(256) void k1_mfma(
    const _Float16* __restrict__ Qh, const _Float16* __restrict__ Klh,
    const _Float16* __restrict__ W2T, _Float16* __restrict__ ctxh)
{
    __shared__ __align__(16) _Float16 Qs[64 * 72];
    __shared__ __align__(16) _Float16 Ps[64 * 136];
    const int s0 = blockIdx.x * 64, bh = blockIdx.y;
    const int b = bh >> 4, h = bh & 15;
    const int t = threadIdx.x;
    const int wave = t >> 6, lane = t & 63;
    const int quad = lane >> 4, l15 = lane & 15;

    {
        const _Float16* qg = Qh + ((size_t)bh * cS + s0) * cHD;
#pragma unroll
        for (int i = 0; i < 2; ++i) {
            int idx = t + i * 256;
            int row = idx >> 3, c8 = idx & 7;
            *reinterpret_cast<f16x8*>(&Qs[row * 72 + c8 * 8]) =
                *reinterpret_cast<const f16x8*>(qg + (size_t)row * cHD + c8 * 8);
        }
    }
    __syncthreads();

    const _Float16* klg = Klh + (size_t)bh * cNL * cHD;
    f32x4 accS[8];
#pragma unroll
    for (int nt = 0; nt < 8; ++nt) accS[nt] = (f32x4){0.f, 0.f, 0.f, 0.f};
#pragma unroll
    for (int k0 = 0; k0 < 2; ++k0) {
        f16x8 aq = *reinterpret_cast<const f16x8*>(&Qs[(wave * 16 + l15) * 72 + k0 * 32 + quad * 8]);
#pragma unroll
        for (int nt = 0; nt < 8; ++nt) {
            f16x8 bk = *reinterpret_cast<const f16x8*>(klg + (size_t)(nt * 16 + l15) * cHD + k0 * 32 + quad * 8);
            accS[nt] = __builtin_amdgcn_mfma_f32_16x16x32_f16(aq, bk, accS[nt], 0, 0, 0);
        }
    }

    float rmax[4] = {-1e30f, -1e30f, -1e30f, -1e30f};
#pragma unroll
    for (int nt = 0; nt < 8; ++nt)
#pragma unroll
        for (int r = 0; r < 4; ++r) rmax[r] = fmaxf(rmax[r], accS[nt][r]);
#pragma unroll
    for (int r = 0; r < 4; ++r)
#pragma unroll
        for (int w = 1; w < 16; w <<= 1) rmax[r] = fmaxf(rmax[r], __shfl_xor(rmax[r], w, 16));
    float rsum[4] = {0.f, 0.f, 0.f, 0.f};
#pragma unroll
    for (int nt = 0; nt < 8; ++nt)
#pragma unroll
        for (int r = 0; r < 4; ++r) { accS[nt][r] = __expf(accS[nt][r] - rmax[r]); rsum[r] += accS[nt][r]; }
#pragma unroll
    for (int r = 0; r < 4; ++r) {
#pragma unroll
        for (int w = 1; w < 16; w <<= 1) rsum[r] += __shfl_xor(rsum[r], w, 16);
        rsum[r] = 1.0f / rsum[r];
    }
#pragma unroll
    for (int nt = 0; nt < 8; ++nt)
#pragma unroll
        for (int r = 0; r < 4; ++r)
            Ps[(wave * 16 + quad * 4 + r) * 136 + nt * 16 + l15] = (_Float16)(accS[nt][r] * rsum[r]);
    __syncthreads();

    const _Float16* wtg = W2T + (size_t)bh * cHD * cNL;
    f32x4 accO[4];
#pragma unroll
    for (int nt = 0; nt < 4; ++nt) accO[nt] = (f32x4){0.f, 0.f, 0.f, 0.f};
#pragma unroll
    for (int k0 = 0; k0 < 4; ++k0) {
        f16x8 ap = *reinterpret_cast<const f16x8*>(&Ps[(wave * 16 + l15) * 136 + k0 * 32 + quad * 8]);
#pragma unroll
        for (int nt = 0; nt < 4; ++nt) {
            f16x8 bw = *reinterpret_cast<const f16x8*>(wtg + (size_t)(nt * 16 + l15) * cNL + k0 * 32 + quad * 8);
            accO[nt] = __builtin_amdgcn_mfma_f32_16x16x32_f16(ap, bw, accO[nt], 0, 0, 0);
        }
    }
#pragma unroll
    for (int nt = 0; nt < 4; ++nt)
#pragma unroll
        for (int r = 0; r < 4; ++r) {
            int s = s0 + wave * 16 + quad * 4 + r;
            int d = nt * 16 + l15;
            ctxh[((size_t)(b * cS) + s) * cD + h * cHD + d] = (_Float16)accO[nt][r];
        }
}

// ---------------------------------------------------------------------------
extern "C" void kernel_launch(void* const* d_in, const int* in_sizes, int n_in,
                              void* d_out, int out_size, void* d_ws, size_t ws_size,
                              hipStream_t stream)
{
    const float* X    = (const float*)d_in[0];
    const float* mask = (const float*)d_in[1];
    const float* Wq   = (const float*)d_in[2];
    const float* bq   = (const float*)d_in[3];
    const float* Wk   = (const float*)d_in[4];
    const float* bk   = (const float*)d_in[5];
    const float* Wv   = (const float*)d_in[6];
    const float* bv   = (const float*)d_in[7];
    const float* Wo   = (const float*)d_in[8];
    const float* bo   = (const float*)d_in[9];
    float* out = (float*)d_out;

    float* ws = (float*)d_ws;
    size_t off = 0;
    const size_t szQKV = (size_t)cBH * cS * cHD;      // 8388608 floats
    const size_t szL   = (size_t)cBH * cNL * cHD;     // 262144
    const size_t szM   = (size_t)cBH * cNL * cNL;     // 524288
    float* Qr   = ws + off; off += szQKV;             // Qh f16 (1st half) | Opart f32 (2nd half)
    float* Kr   = ws + off; off += szQKV;             // Kh f16 (1st half) | ctxh f16 (2nd half)
    float* Vr   = ws + off; off += szQKV;             // Vh f16 (1st half) | VTh f16 (2nd half)
    _Float16* Xh  = (_Float16*)(ws + off); off += szQKV / 2;
    _Float16* WqT = (_Float16*)(ws + off); off += 524288;
    _Float16* WkT = (_Float16*)(ws + off); off += 524288;
    _Float16* WvT = (_Float16*)(ws + off); off += 524288;
    _Float16* WoT = (_Float16*)(ws + off); off += 524288;
    float* Xm   = ws + off; off += (size_t)cB * cNL * cHID;
    float* mbar = ws + off; off += 256;
    float* Ql  = ws + off; off += szL;
    float* Kl  = ws + off; off += szL;
    float* k2  = ws + off; off += szM;
    float* Mg0 = ws + off; off += szM;                // M double-buffer 0
    float* Mg1 = ws + off; off += szM;                // M double-buffer 1
    float* T1b = ws + off; off += szM;                // (unused)
    float* T2b = ws + off; off += szM;                // (unused)
    float* T3b = ws + off; off += szM;                // (unused)
    float* CV  = ws + off; off += szL;                // (unused now)
    _Float16* Qlh  = (_Float16*)(ws + off); off += szL / 2;
    _Float16* Klh  = (_Float16*)(ws + off); off += szL / 2;
    _Float16* W2Th = (_Float16*)(ws + off); off += szL / 2;
    int*   cmax = (int*)(ws + off); off += 16;
    float* mpart = ws + off; off += 65536;
    float* spart = ws + off; off += 65536;

    _Float16* Qh   = (_Float16*)Qr;
    float*    Opart = Qr + szQKV / 2;        // 2nd half of Q region (Qh untouched)
    _Float16* Kh   = (_Float16*)Kr;
    _Float16* ctxh = (_Float16*)(Kr + szQKV / 2);   // 2nd half of K region
    _Float16* Vh   = (_Float16*)Vr;
    _Float16* VTh  = (_Float16*)(Vr + szQKV / 2);   // 2nd half of V region

    (void)T1b; (void)T2b; (void)T3b; (void)CV;

    hipMemsetAsync(cmax, 0, sizeof(int), stream);

    wcast_t<<<dim3(32, 32, 4), 256, 0, stream>>>(Wq, Wk, Wv, Wo, WqT, WkT, WvT, WoT);
    xm_kernel<<<dim3(cB * cNL, 4), 64, 0, stream>>>(X, mask, Xm, mbar, Xh);

    qkv_gemm_f16<<<dim3(512, 1, 3), 256, 0, stream>>>(
        Xh, mask, WqT, WkT, WvT, bq, bk, bv, Qh, Kh, Vh);
    vtrans<<<dim3(cS / 64, cBH), 256, 0, stream>>>(Vh, VTh);
    lgemm<<<dim3(cD / 64, (cB * cNL) / 64, 2), 256, 0, stream>>>(Xm, mbar, Wq, bq, Wk, bk, Ql, Kl, Qlh, Klh);

    k2_softmax<<<cBH * cNL, 128, 0, stream>>>(Ql, Kl, k2);
    colsum_max<<<cBH, 128, 0, stream>>>(k2, cmax);

    // fused: Newton-Schulz (32 blocks, R8 internals) overlapped with k3v
    // flash-prefill (256 blocks x 2 chunks, barrier-free)
    nys_k3v<<<dim3(32 + 256), 512, 0, stream>>>(
        k2, cmax, Mg0, Mg1, Qlh, Kh, VTh, mask, Opart, mpart, spart);

    // W2 = (K^T/c) @ M6 @ (reduced CV), reduce fused in
    w2_matmul<<<cBH, 256, 0, stream>>>(k2, Mg1, cmax, Opart, mpart, spart, W2Th);
    k1_mfma<<<dim3(cS / 64, cBH), 256, 0, stream>>>(Qh, Klh, W2Th, ctxh);
    out_gemm_f16<<<dim3(512), 256, 0, stream>>>(ctxh, WoT, bo, out);
}

// Round 11
// 451.321 us; speedup vs baseline: 1.1512x; 1.0557x over previous
//
#include <hip/hip_runtime.h>
#include <math.h>

// Problem constants
constexpr int cB = 2, cS = 4096, cHID = 1024, cNH = 16, cHD = 64, cNL = 128, cSEG = 32, cD = 1024, cBH = 32;
constexpr float cSCALE = 0.35355339059327373f;   // 1/sqrt(sqrt(64))

typedef _Float16 f16x8 __attribute__((ext_vector_type(8)));
typedef float f32x4 __attribute__((ext_vector_type(4)));

__device__ inline void gload_lds16(const void* g, void* l) {
    __builtin_amdgcn_global_load_lds(
        (const __attribute__((address_space(1))) void*)g,
        (__attribute__((address_space(3))) void*)l, 16, 0, 0);
}

// ---------------------------------------------------------------------------
// transpose+cast W (K x N fp32) -> WT (N x K fp16)
// ---------------------------------------------------------------------------
__global__ __launch_bounds__(256) void wcast_t(
    const float* __restrict__ Wq, const float* __restrict__ Wk,
    const float* __restrict__ Wv, const float* __restrict__ Wo,
    _Float16* __restrict__ WqT, _Float16* __restrict__ WkT,
    _Float16* __restrict__ WvT, _Float16* __restrict__ WoT)
{
    __shared__ float tile[32][33];
    const int wsel = blockIdx.z;
    const float* W = (wsel == 0) ? Wq : (wsel == 1 ? Wk : (wsel == 2 ? Wv : Wo));
    _Float16* WT   = (wsel == 0) ? WqT : (wsel == 1 ? WkT : (wsel == 2 ? WvT : WoT));
    const int n0 = blockIdx.x * 32, k0 = blockIdx.y * 32;
    const int t = threadIdx.x;
    const int r = t >> 3, c = (t & 7) * 4;
    float4 v = *reinterpret_cast<const float4*>(W + (size_t)(k0 + r) * cD + n0 + c);
    tile[r][c] = v.x; tile[r][c + 1] = v.y; tile[r][c + 2] = v.z; tile[r][c + 3] = v.w;
    __syncthreads();
    union { _Float16 h[4]; ushort4 u; } p;
    p.h[0] = (_Float16)tile[c + 0][r]; p.h[1] = (_Float16)tile[c + 1][r];
    p.h[2] = (_Float16)tile[c + 2][r]; p.h[3] = (_Float16)tile[c + 3][r];
    *reinterpret_cast<ushort4*>(WT + (size_t)(n0 + r) * cHID + k0 + c) = p.u;
}

// ---------------------------------------------------------------------------
// xm_kernel (+fused cast_x), 4x D-split: grid (256, 4) x 64 thr.
// ---------------------------------------------------------------------------
__global__ __launch_bounds__(64) void xm_kernel(
    const float* __restrict__ X, const float* __restrict__ mask,
    float* __restrict__ Xm, float* __restrict__ mbar, _Float16* __restrict__ Xh)
{
    const int bl = blockIdx.x;          // b*128 + l
    const int q  = blockIdx.y;          // D quarter
    const int b = bl >> 7, l = bl & 127;
    const int c = q * 256 + threadIdx.x * 4;
    float4 a = {0.f, 0.f, 0.f, 0.f};
    float msum = 0.f;
    for (int j = 0; j < cSEG; ++j) {
        float m = mask[b * cS + l * cSEG + j];
        size_t roff = ((size_t)(b * cS + l * cSEG + j)) * cHID + c;
        float4 x = *reinterpret_cast<const float4*>(X + roff);
        union { _Float16 h[4]; ushort4 u; } p;
        p.h[0] = (_Float16)x.x; p.h[1] = (_Float16)x.y;
        p.h[2] = (_Float16)x.z; p.h[3] = (_Float16)x.w;
        *reinterpret_cast<ushort4*>(Xh + roff) = p.u;
        a.x += m * x.x; a.y += m * x.y; a.z += m * x.z; a.w += m * x.w;
        msum += m;
    }
    const float inv = 1.0f / cSEG;
    a.x *= inv; a.y *= inv; a.z *= inv; a.w *= inv;
    *reinterpret_cast<float4*>(Xm + (size_t)bl * cHID + c) = a;
    if (q == 0 && threadIdx.x == 0) mbar[bl] = msum * inv;
}

// ---------------------------------------------------------------------------
// f16 MFMA GEMM: out = ctxh @ Wo + bo  (BK=64, swizzled, XCD-aware), grid 512
// ---------------------------------------------------------------------------
__global__ __launch_bounds__(256) void out_gemm_f16(
    const _Float16* __restrict__ Ah, const _Float16* __restrict__ WT,
    const float* __restrict__ bias, float* __restrict__ Y)
{
    __shared__ __align__(16) _Float16 As[128 * 64];
    __shared__ __align__(16) _Float16 Bs[128 * 64];
    const int orig = blockIdx.x;
    const int xcd = orig & 7, idx = orig >> 3;
    const int n0 = (idx & 7) * 128;
    const int m0 = (xcd * 8 + (idx >> 3)) * 128;
    const int t = threadIdx.x;
    const int wave = t >> 6, lane = t & 63;
    const int wm = (wave >> 1) * 64, wn = (wave & 1) * 64;
    const int quad = lane >> 4, l15 = lane & 15;
    const int srow = wave * 8 + (lane >> 3);
    const int scol = ((lane & 7) ^ (lane >> 3)) * 8;

    f32x4 acc[4][4];
#pragma unroll
    for (int i = 0; i < 4; ++i)
#pragma unroll
        for (int j = 0; j < 4; ++j) acc[i][j] = (f32x4){0.f, 0.f, 0.f, 0.f};

    for (int k0 = 0; k0 < cD; k0 += 64) {
        const _Float16* aSrc = Ah + (size_t)(m0 + srow) * cD + k0 + scol;
        const _Float16* bSrc = WT + (size_t)(n0 + srow) * cD + k0 + scol;
#pragma unroll
        for (int i = 0; i < 4; ++i) {
            gload_lds16(aSrc + (size_t)(i * 32) * cD, &As[(wave * 8 + i * 32) * 64]);
            gload_lds16(bSrc + (size_t)(i * 32) * cD, &Bs[(wave * 8 + i * 32) * 64]);
        }
        __syncthreads();
        f16x8 af[2][4], bf[2][4];
#pragma unroll
        for (int kh = 0; kh < 2; ++kh) {
            const int cg = ((kh * 4 + quad) ^ (l15 & 7)) * 8;
#pragma unroll
            for (int mt = 0; mt < 4; ++mt)
                af[kh][mt] = *reinterpret_cast<const f16x8*>(&As[(wm + mt * 16 + l15) * 64 + cg]);
#pragma unroll
            for (int nt = 0; nt < 4; ++nt)
                bf[kh][nt] = *reinterpret_cast<const f16x8*>(&Bs[(wn + nt * 16 + l15) * 64 + cg]);
        }
#pragma unroll
        for (int kh = 0; kh < 2; ++kh)
#pragma unroll
            for (int mt = 0; mt < 4; ++mt)
#pragma unroll
                for (int nt = 0; nt < 4; ++nt)
                    acc[mt][nt] = __builtin_amdgcn_mfma_f32_16x16x32_f16(af[kh][mt], bf[kh][nt], acc[mt][nt], 0, 0, 0);
        __syncthreads();
    }
#pragma unroll
    for (int mt = 0; mt < 4; ++mt) {
#pragma unroll
        for (int r = 0; r < 4; ++r) {
            int R = m0 + wm + mt * 16 + quad * 4 + r;
#pragma unroll
            for (int nt = 0; nt < 4; ++nt) {
                int Cc = n0 + wn + nt * 16 + l15;
                Y[(size_t)R * cHID + Cc] = acc[mt][nt][r] + bias[Cc];
            }
        }
    }
}

// ---------------------------------------------------------------------------
// Landmark GEMM (fp32, exact path). Emits f16 Qlh/Klh for MFMA consumers.
// ---------------------------------------------------------------------------
__global__ __launch_bounds__(256) void lgemm(
    const float* __restrict__ Xm, const float* __restrict__ mbar,
    const float* __restrict__ Wq, const float* __restrict__ bq,
    const float* __restrict__ Wk, const float* __restrict__ bk,
    float* __restrict__ Ql, float* __restrict__ Kl,
    _Float16* __restrict__ Qlh, _Float16* __restrict__ Klh)
{
    __shared__ __align__(16) float As[16][68];
    __shared__ __align__(16) float Bs[16][68];
    const int tid = threadIdx.x;
    const int wsel = blockIdx.z;
    const float* W    = wsel ? Wk : Wq;
    const float* bias = wsel ? bk : bq;
    float* Yl         = wsel ? Kl : Ql;
    _Float16* Ylh     = wsel ? Klh : Qlh;
    const int c0 = blockIdx.x * 64, r0 = blockIdx.y * 64;
    const int tx = tid & 15, ty = tid >> 4;
    const int am = tid >> 2, ak = (tid & 3) * 4;
    const int bkk = tid >> 4, bn = (tid & 15) * 4;

    float acc[4][4] = {};
    for (int k0 = 0; k0 < cHID; k0 += 16) {
        float4 a4 = *reinterpret_cast<const float4*>(Xm + (size_t)(r0 + am) * cHID + k0 + ak);
        As[ak + 0][am] = a4.x; As[ak + 1][am] = a4.y; As[ak + 2][am] = a4.z; As[ak + 3][am] = a4.w;
        float4 b4 = *reinterpret_cast<const float4*>(W + (size_t)(k0 + bkk) * cD + c0 + bn);
        *reinterpret_cast<float4*>(&Bs[bkk][bn]) = b4;
        __syncthreads();
#pragma unroll
        for (int kk = 0; kk < 16; ++kk) {
            float4 av  = *reinterpret_cast<const float4*>(&As[kk][ty * 4]);
            float4 bv4 = *reinterpret_cast<const float4*>(&Bs[kk][tx * 4]);
            float a_[4] = {av.x, av.y, av.z, av.w};
            float b_[4] = {bv4.x, bv4.y, bv4.z, bv4.w};
#pragma unroll
            for (int i = 0; i < 4; ++i)
#pragma unroll
                for (int j = 0; j < 4; ++j) acc[i][j] += a_[i] * b_[j];
        }
        __syncthreads();
    }
#pragma unroll
    for (int i = 0; i < 4; ++i) {
        int r = r0 + ty * 4 + i;          // b*128 + l
        int b = r >> 7, l = r & 127;
        float mb = mbar[r];
#pragma unroll
        for (int j = 0; j < 4; ++j) {
            int c = c0 + tx * 4 + j;
            int h = c >> 6, d = c & 63;
            float val = (acc[i][j] + mb * bias[c]) * cSCALE;
            size_t idx = ((size_t)(b * cNH + h) * cNL + l) * cHD + d;
            Yl[idx] = val;
            Ylh[idx] = (_Float16)val;
        }
    }
}

// ---------------------------------------------------------------------------
// k2 softmax chain (fp32-clean path)
// ---------------------------------------------------------------------------
__global__ __launch_bounds__(128) void k2_softmax(
    const float* __restrict__ Ql, const float* __restrict__ Kl, float* __restrict__ k2)
{
    __shared__ __align__(16) float qrow[64];
    __shared__ float red[128];
    int bh = blockIdx.x >> 7, i = blockIdx.x & 127;
    int j = threadIdx.x;
    if (j < 64) qrow[j] = Ql[(bh * cNL + i) * cHD + j];
    __syncthreads();
    const float4* q4  = reinterpret_cast<const float4*>(qrow);
    const float4* kl4 = reinterpret_cast<const float4*>(Kl + (bh * cNL + j) * cHD);
    float dot = 0.f;
#pragma unroll
    for (int u = 0; u < 16; ++u) {
        float4 a = q4[u], b = kl4[u];
        dot += a.x * b.x + a.y * b.y + a.z * b.z + a.w * b.w;
    }
    red[j] = dot; __syncthreads();
    for (int off = 64; off > 0; off >>= 1) { if (j < off) red[j] = fmaxf(red[j], red[j + off]); __syncthreads(); }
    float m = red[0]; __syncthreads();
    float e = expf(dot - m);
    red[j] = e; __syncthreads();
    for (int off = 64; off > 0; off >>= 1) { if (j < off) red[j] += red[j + off]; __syncthreads(); }
    k2[(bh * cNL + i) * cNL + j] = e / red[0];
}

__global__ __launch_bounds__(128) void colsum_max(const float* __restrict__ k2, int* __restrict__ cmax)
{
    __shared__ float red[128];
    int bh = blockIdx.x, j = threadIdx.x;
    float s = 0.f;
    for (int i = 0; i < cNL; ++i) s += k2[(bh * cNL + i) * cNL + j];
    red[j] = s; __syncthreads();
    for (int off = 64; off > 0; off >>= 1) { if (j < off) red[j] = fmaxf(red[j], red[j + off]); __syncthreads(); }
    if (j == 0) atomicMax(cmax, __float_as_int(red[0]));
}

// ---------------------------------------------------------------------------
// Helpers for fused nys+qkv
// ---------------------------------------------------------------------------
__device__ inline void split2(float v, _Float16& h, _Float16& l) {
    h = (_Float16)v;
    l = (_Float16)(v - (float)h);
}
__device__ inline unsigned short f16bits(_Float16 h) { return __builtin_bit_cast(unsigned short, h); }

#define NYS_MFMA(a, b, c) __builtin_amdgcn_mfma_f32_16x16x32_f16((a), (b), (c), 0, 0, 0)

// preload left frags: rows wr*64 + mt*16 + l15 (mt 0..3), contiguous b128
#define NYS_PRELOAD(PH, PL, LH, LL)                                                     \
    {                                                                                   \
        _Pragma("unroll")                                                               \
        for (int mt_ = 0; mt_ < 4; ++mt_) {                                             \
            const int rowL_ = wr * 64 + mt_ * 16 + l15;                                 \
            _Pragma("unroll")                                                           \
            for (int k0_ = 0; k0_ < 4; ++k0_) {                                         \
                LH[mt_][k0_] = *reinterpret_cast<const f16x8*>(&PH[rowL_ * 136 + k0_ * 32 + quad * 8]); \
                LL[mt_][k0_] = *reinterpret_cast<const f16x8*>(&PL[rowL_ * 136 + k0_ * 32 + quad * 8]); \
            }                                                                           \
        }                                                                               \
    }

// product over wave's 64x32 region; 3-term split (HH + LH + HL)
#define NYS_PRODUCT(PH, PL, LH, LL)                                                     \
    {                                                                                   \
        _Pragma("unroll")                                                               \
        for (int mt_ = 0; mt_ < 4; ++mt_)                                               \
            _Pragma("unroll")                                                           \
            for (int nt_ = 0; nt_ < 2; ++nt_) acc[mt_][nt_] = (f32x4){0.f, 0.f, 0.f, 0.f}; \
        _Pragma("unroll")                                                               \
        for (int nt_ = 0; nt_ < 2; ++nt_) {                                             \
            _Pragma("unroll")                                                           \
            for (int k0_ = 0; k0_ < 4; ++k0_) {                                         \
                const int boff_ = (wcb + nt_ * 16) * 136 + k0_ * 32 + quad * 8;         \
                f16x8 bh_ = *reinterpret_cast<const f16x8*>(&PH[boff_]);                \
                f16x8 bl_ = *reinterpret_cast<const f16x8*>(&PL[boff_]);                \
                _Pragma("unroll")                                                       \
                for (int mt_ = 0; mt_ < 4; ++mt_) {                                     \
                    acc[mt_][nt_] = NYS_MFMA(LH[mt_][k0_], bh_, acc[mt_][nt_]);         \
                    acc[mt_][nt_] = NYS_MFMA(LL[mt_][k0_], bh_, acc[mt_][nt_]);         \
                    acc[mt_][nt_] = NYS_MFMA(LH[mt_][k0_], bl_, acc[mt_][nt_]);         \
                }                                                                       \
            }                                                                           \
        }                                                                               \
    }

// ---------------------------------------------------------------------------
// nys_qkv fused: blocks [0,32) run the R8-verified Newton-Schulz (A+W planes
// in 136KB LDS, 8 waves). Blocks [32,800) run the QKV GEMM as 512-thread
// dual-tile blocks: each 256-thread half executes the verified 128x128 tile
// loop in its own 32KB slice of SMEM. nys and qkv are data-independent, so
// nys's 32 CUs hide entirely under the ~768-block qkv wave.
// Job map (r = bid-32): wsel=r/256; rr=r%256; xcd=rr&7 (==bid%8); q=rr>>3;
// mtile=xcd*8+(q>>2); ntile=(q&3)*2+half.
// ---------------------------------------------------------------------------
__global__ __launch_bounds__(512, 2) void nys_qkv(
    const float* __restrict__ k2, const int* __restrict__ cmax,
    float* __restrict__ Mg0, float* __restrict__ Mg1,
    const _Float16* __restrict__ Xh, const float* __restrict__ mask,
    const _Float16* __restrict__ WqT, const _Float16* __restrict__ WkT, const _Float16* __restrict__ WvT,
    const float* __restrict__ bq, const float* __restrict__ bk, const float* __restrict__ bv,
    _Float16* __restrict__ Qh, _Float16* __restrict__ Kh, _Float16* __restrict__ Vh)
{
    __shared__ __align__(16) _Float16 SMEM[4 * 128 * 136];   // 136 KB

    if (blockIdx.x < 32) {
        // ================= NYS role (R8 v5, verified) =================
        _Float16* Ahi_s = SMEM;
        _Float16* Alo_s = SMEM + 128 * 136;
        _Float16* Whi_s = SMEM + 2 * 128 * 136;
        _Float16* Wlo_s = SMEM + 3 * 128 * 136;
        const int bh = blockIdx.x;
        const int t = threadIdx.x;
        const int wave = t >> 6, lane = t & 63;
        const int wr = wave >> 2, wc = wave & 3;
        const int quad = lane >> 4, l15 = lane & 15;
        const int wcb = wc * 32 + l15;
        const float* Kg = k2 + (size_t)bh * 16384;
        float* Mg0b = Mg0 + (size_t)bh * 16384;
        float* Mg1b = Mg1 + (size_t)bh * 16384;
        const float sc = sqrtf(1.0f / __int_as_float(*cmax));

        {
            const int row = t >> 2, c0 = (t & 3) * 32;
            const float* src = Kg + row * 128 + c0;
            _Float16* dh = &Whi_s[row * 136 + c0];
            _Float16* dl = &Wlo_s[row * 136 + c0];
#pragma unroll
            for (int u = 0; u < 32; u += 4) {
                float4 v = *reinterpret_cast<const float4*>(src + u);
                ushort4 ph, pl; _Float16 h, l;
                split2(v.x * sc, h, l); ph.x = f16bits(h); pl.x = f16bits(l);
                split2(v.y * sc, h, l); ph.y = f16bits(h); pl.y = f16bits(l);
                split2(v.z * sc, h, l); ph.z = f16bits(h); pl.z = f16bits(l);
                split2(v.w * sc, h, l); ph.w = f16bits(h); pl.w = f16bits(l);
                *reinterpret_cast<ushort4*>(dh + u) = ph;
                *reinterpret_cast<ushort4*>(dl + u) = pl;
            }
        }
        __syncthreads();

        f32x4 acc[4][2];
        f16x8 Fh[4][4], Fl[4][4];

        NYS_PRELOAD(Whi_s, Wlo_s, Fh, Fl);
        NYS_PRODUCT(Whi_s, Wlo_s, Fh, Fl);
#pragma unroll
        for (int mt = 0; mt < 4; ++mt)
#pragma unroll
            for (int nt = 0; nt < 2; ++nt) {
                const int col = wcb + nt * 16;
                const int rb  = wr * 64 + mt * 16 + quad * 4;
                ushort4 ph, pl;
#pragma unroll
                for (int r = 0; r < 4; ++r) {
                    _Float16 h, l; split2(acc[mt][nt][r], h, l);
                    ((unsigned short*)&ph)[r] = f16bits(h);
                    ((unsigned short*)&pl)[r] = f16bits(l);
                }
                *reinterpret_cast<ushort4*>(&Ahi_s[col * 136 + rb]) = ph;
                *reinterpret_cast<ushort4*>(&Alo_s[col * 136 + rb]) = pl;
            }
        __syncthreads();

        for (int it = 0; it < 6; ++it) {
            NYS_PRELOAD(Ahi_s, Alo_s, Fh, Fl);
            NYS_PRODUCT(Ahi_s, Alo_s, Fh, Fl);
#pragma unroll
            for (int mt = 0; mt < 4; ++mt)
#pragma unroll
                for (int nt = 0; nt < 2; ++nt) {
                    const int col = wcb + nt * 16;
                    const int rb  = wr * 64 + mt * 16 + quad * 4;
                    ushort4 ah = *reinterpret_cast<const ushort4*>(&Ahi_s[col * 136 + rb]);
                    ushort4 al = *reinterpret_cast<const ushort4*>(&Alo_s[col * 136 + rb]);
                    ushort4 ph, pl;
#pragma unroll
                    for (int r = 0; r < 4; ++r) {
                        float av = (float)__builtin_bit_cast(_Float16, ((unsigned short*)&ah)[r])
                                 + (float)__builtin_bit_cast(_Float16, ((unsigned short*)&al)[r]);
                        float v = ((rb + r) == col ? 15.0f : 0.0f) - 7.0f * av + acc[mt][nt][r];
                        _Float16 h, l; split2(v, h, l);
                        ((unsigned short*)&ph)[r] = f16bits(h);
                        ((unsigned short*)&pl)[r] = f16bits(l);
                    }
                    *reinterpret_cast<ushort4*>(&Whi_s[col * 136 + rb]) = ph;
                    *reinterpret_cast<ushort4*>(&Wlo_s[col * 136 + rb]) = pl;
                }
            __syncthreads();                       // #1: B2 visible
            NYS_PRODUCT(Whi_s, Wlo_s, Fh, Fl);
            __syncthreads();                       // #2: B2 reads done
#pragma unroll
            for (int mt = 0; mt < 4; ++mt)
#pragma unroll
                for (int nt = 0; nt < 2; ++nt) {
                    const int col = wcb + nt * 16;
                    const int rb  = wr * 64 + mt * 16 + quad * 4;
                    ushort4 ph, pl; float4 mv;
#pragma unroll
                    for (int r = 0; r < 4; ++r) {
                        float v = ((rb + r) == col ? 13.0f : 0.0f) - acc[mt][nt][r];
                        _Float16 h, l; split2(v, h, l);
                        ((unsigned short*)&ph)[r] = f16bits(h);
                        ((unsigned short*)&pl)[r] = f16bits(l);
                        ((float*)&mv)[r] = 0.25f * v;
                    }
                    *reinterpret_cast<ushort4*>(&Whi_s[col * 136 + rb]) = ph;
                    *reinterpret_cast<ushort4*>(&Wlo_s[col * 136 + rb]) = pl;
                    if (it == 0)
                        *reinterpret_cast<float4*>(&Mg0b[col * 128 + rb]) = mv;
                }
            __syncthreads();                       // #3: B3 visible
            NYS_PRODUCT(Whi_s, Wlo_s, Fh, Fl);
#pragma unroll
            for (int mt = 0; mt < 4; ++mt)
#pragma unroll
                for (int nt = 0; nt < 2; ++nt) {
                    const int col = wcb + nt * 16;
                    const int rb  = wr * 64 + mt * 16 + quad * 4;
                    ushort4 ph, pl;
#pragma unroll
                    for (int r = 0; r < 4; ++r) {
                        _Float16 h, l; split2(0.25f * acc[mt][nt][r], h, l);
                        ((unsigned short*)&ph)[r] = f16bits(h);
                        ((unsigned short*)&pl)[r] = f16bits(l);
                    }
                    *reinterpret_cast<ushort4*>(&Ahi_s[col * 136 + rb]) = ph;
                    *reinterpret_cast<ushort4*>(&Alo_s[col * 136 + rb]) = pl;
                }
            if (it >= 1) {
                const float* Mr = (it & 1) ? Mg0b : Mg1b;
                float*       Mw = (it & 1) ? Mg1b : Mg0b;
#pragma unroll
                for (int mt = 0; mt < 4; ++mt)
#pragma unroll
                    for (int nt = 0; nt < 2; ++nt) acc[mt][nt] = (f32x4){0.f, 0.f, 0.f, 0.f};
#pragma unroll
                for (int k0 = 0; k0 < 4; ++k0) {
                    f16x8 Mh[4], Ml[4];
#pragma unroll
                    for (int mt = 0; mt < 4; ++mt) {
                        const int rowL = wr * 64 + mt * 16 + l15;
                        const float* src = Mr + rowL * 128 + k0 * 32 + quad * 8;
                        float4 v0 = *reinterpret_cast<const float4*>(src);
                        float4 v1 = *reinterpret_cast<const float4*>(src + 4);
                        union { f16x8 v; _Float16 e[8]; } hh, ll;
                        split2(v0.x, hh.e[0], ll.e[0]); split2(v0.y, hh.e[1], ll.e[1]);
                        split2(v0.z, hh.e[2], ll.e[2]); split2(v0.w, hh.e[3], ll.e[3]);
                        split2(v1.x, hh.e[4], ll.e[4]); split2(v1.y, hh.e[5], ll.e[5]);
                        split2(v1.z, hh.e[6], ll.e[6]); split2(v1.w, hh.e[7], ll.e[7]);
                        Mh[mt] = hh.v; Ml[mt] = ll.v;
                    }
#pragma unroll
                    for (int nt = 0; nt < 2; ++nt) {
                        const int boff = (wcb + nt * 16) * 136 + k0 * 32 + quad * 8;
                        f16x8 bh_ = *reinterpret_cast<const f16x8*>(&Whi_s[boff]);
                        f16x8 bl_ = *reinterpret_cast<const f16x8*>(&Wlo_s[boff]);
#pragma unroll
                        for (int mt = 0; mt < 4; ++mt) {
                            acc[mt][nt] = NYS_MFMA(Mh[mt], bh_, acc[mt][nt]);
                            acc[mt][nt] = NYS_MFMA(Ml[mt], bh_, acc[mt][nt]);
                            acc[mt][nt] = NYS_MFMA(Mh[mt], bl_, acc[mt][nt]);
                        }
                    }
                }
#pragma unroll
                for (int mt = 0; mt < 4; ++mt)
#pragma unroll
                    for (int nt = 0; nt < 2; ++nt) {
                        const int col = wcb + nt * 16;
                        const int rb  = wr * 64 + mt * 16 + quad * 4;
                        float4 mv;
#pragma unroll
                        for (int r = 0; r < 4; ++r) ((float*)&mv)[r] = 0.25f * acc[mt][nt][r];
                        *reinterpret_cast<float4*>(&Mw[col * 128 + rb]) = mv;
                    }
            }
            __syncthreads();                       // #4: A'/M' visible; W free
        }
        // M6 ends in Mg1.
    } else {
        // ============ QKV role (dual 128x128 tiles per 512-thr block) ============
        const int half = threadIdx.x >> 8;          // 0/1
        const int t = threadIdx.x & 255;
        _Float16* As = SMEM + (size_t)half * 16384;           // 128*64 f16
        _Float16* Bs = As + 8192;
        const int r = blockIdx.x - 32;              // 0..767
        const int wsel = r >> 8;                    // /256
        const int rr = r & 255;
        const int xcd = rr & 7;
        const int q = rr >> 3;                      // 0..31
        const int mtile = xcd * 8 + (q >> 2);
        const int ntile = (q & 3) * 2 + half;
        const int m0 = mtile * 128, n0 = ntile * 128;
        const _Float16* WT = (wsel == 0) ? WqT : (wsel == 1 ? WkT : WvT);
        const float* bias  = (wsel == 0) ? bq  : (wsel == 1 ? bk  : bv);
        _Float16* Y        = (wsel == 0) ? Qh  : (wsel == 1 ? Kh  : Vh);

        const int wave = t >> 6, lane = t & 63;
        const int wm = (wave >> 1) * 64, wn = (wave & 1) * 64;
        const int quad = lane >> 4, l15 = lane & 15;
        const int srow = wave * 8 + (lane >> 3);
        const int scol = ((lane & 7) ^ (lane >> 3)) * 8;

        f32x4 acc[4][4];
#pragma unroll
        for (int i = 0; i < 4; ++i)
#pragma unroll
            for (int j = 0; j < 4; ++j) acc[i][j] = (f32x4){0.f, 0.f, 0.f, 0.f};

        for (int k0 = 0; k0 < cHID; k0 += 64) {
            const _Float16* aSrc = Xh + (size_t)(m0 + srow) * cHID + k0 + scol;
            const _Float16* bSrc = WT + (size_t)(n0 + srow) * cHID + k0 + scol;
#pragma unroll
            for (int i = 0; i < 4; ++i) {
                gload_lds16(aSrc + (size_t)(i * 32) * cHID, &As[(wave * 8 + i * 32) * 64]);
                gload_lds16(bSrc + (size_t)(i * 32) * cHID, &Bs[(wave * 8 + i * 32) * 64]);
            }
            __syncthreads();
            f16x8 af[2][4], bf[2][4];
#pragma unroll
            for (int kh = 0; kh < 2; ++kh) {
                const int cg = ((kh * 4 + quad) ^ (l15 & 7)) * 8;
#pragma unroll
                for (int mt = 0; mt < 4; ++mt)
                    af[kh][mt] = *reinterpret_cast<const f16x8*>(&As[(wm + mt * 16 + l15) * 64 + cg]);
#pragma unroll
                for (int nt = 0; nt < 4; ++nt)
                    bf[kh][nt] = *reinterpret_cast<const f16x8*>(&Bs[(wn + nt * 16 + l15) * 64 + cg]);
            }
#pragma unroll
            for (int kh = 0; kh < 2; ++kh)
#pragma unroll
                for (int mt = 0; mt < 4; ++mt)
#pragma unroll
                    for (int nt = 0; nt < 4; ++nt)
                        acc[mt][nt] = __builtin_amdgcn_mfma_f32_16x16x32_f16(af[kh][mt], bf[kh][nt], acc[mt][nt], 0, 0, 0);
            __syncthreads();
        }
#pragma unroll
        for (int mt = 0; mt < 4; ++mt) {
#pragma unroll
            for (int rI = 0; rI < 4; ++rI) {
                int R = m0 + wm + mt * 16 + quad * 4 + rI;
                int b = R >> 12, s = R & (cS - 1);
                float msc = (wsel < 2) ? mask[b * cS + s] * cSCALE : 1.0f;
#pragma unroll
                for (int nt = 0; nt < 4; ++nt) {
                    int Cc = n0 + wn + nt * 16 + l15;
                    int h = Cc >> 6, d = Cc & 63;
                    float val = (acc[mt][nt][rI] + bias[Cc]) * msc;
                    Y[((size_t)(b * cNH + h) * cS + s) * cHD + d] = (_Float16)val;
                }
            }
        }
    }
}

// ---------------------------------------------------------------------------
// vtrans: Vh[bh][s][d] f16 -> VTh[bh][d][s] f16 (64x64 LDS tiles)
// ---------------------------------------------------------------------------
__global__ __launch_bounds__(256) void vtrans(const _Float16* __restrict__ Vh, _Float16* __restrict__ VTh)
{
    __shared__ ushort T[64][72];
    const int s0 = blockIdx.x * 64, bh = blockIdx.y;
    const int t = threadIdx.x;
    const _Float16* vb = Vh + ((size_t)bh * cS + s0) * cHD;
#pragma unroll
    for (int i = 0; i < 2; ++i) {
        int idx = t + i * 256;
        int row = idx >> 3, c8 = idx & 7;
        f16x8 v = *reinterpret_cast<const f16x8*>(vb + (size_t)row * cHD + c8 * 8);
#pragma unroll
        for (int j = 0; j < 8; ++j) T[row][c8 * 8 + j] = ((ushort*)&v)[j];
    }
    __syncthreads();
    _Float16* vt = VTh + (size_t)bh * cHD * cS;
#pragma unroll
    for (int i = 0; i < 2; ++i) {
        int idx = t + i * 256;
        int d = idx >> 3, s8 = idx & 7;
        f16x8 o;
#pragma unroll
        for (int j = 0; j < 8; ++j) ((ushort*)&o)[j] = T[s8 * 8 + j][d];
        *reinterpret_cast<f16x8*>(vt + (size_t)d * cS + s0 + s8 * 8) = o;
    }
}

// ---------------------------------------------------------------------------
// k3v_mfma: flash-prefill over landmarks (R8-verified). grid (16, 32), 4 waves.
// ---------------------------------------------------------------------------
__global__ __launch_bounds__(256) void k3v_mfma(
    const _Float16* __restrict__ Qlh, const _Float16* __restrict__ Kh,
    const _Float16* __restrict__ VTh, const float* __restrict__ mask,
    float* __restrict__ Opart, float* __restrict__ mpart, float* __restrict__ spart)
{
    __shared__ __align__(16) _Float16 Ps[128 * 72];
    __shared__ float msk[256];
    const int z = blockIdx.x, bh = blockIdx.y;
    const int b = bh >> 4;
    const int sbase = z * 256;
    const int t = threadIdx.x;
    const int wave = t >> 6, lane = t & 63;
    const int quad = lane >> 4, l15 = lane & 15;

    msk[t] = mask[b * cS + sbase + t];

    f16x8 aq[2][2];
    const _Float16* qlg = Qlh + (size_t)bh * cNL * cHD;
#pragma unroll
    for (int mt = 0; mt < 2; ++mt)
#pragma unroll
        for (int k0 = 0; k0 < 2; ++k0)
            aq[mt][k0] = *reinterpret_cast<const f16x8*>(
                qlg + (size_t)(wave * 32 + mt * 16 + l15) * cHD + k0 * 32 + quad * 8);

    float mrun[2][4], srun[2][4];
    f32x4 accO[2][4];
#pragma unroll
    for (int mt = 0; mt < 2; ++mt)
#pragma unroll
        for (int r = 0; r < 4; ++r) { mrun[mt][r] = -1e30f; srun[mt][r] = 0.f; }
#pragma unroll
    for (int mt = 0; mt < 2; ++mt)
#pragma unroll
        for (int dt = 0; dt < 4; ++dt) accO[mt][dt] = (f32x4){0.f, 0.f, 0.f, 0.f};

    __syncthreads();   // msk visible

    const _Float16* kg = Kh + (size_t)bh * cS * cHD;
    const _Float16* vg = VTh + (size_t)bh * cHD * cS;

    for (int step = 0; step < 4; ++step) {
        const int st = sbase + step * 64;
        f32x4 accS[2][4];
#pragma unroll
        for (int mt = 0; mt < 2; ++mt)
#pragma unroll
            for (int nt = 0; nt < 4; ++nt) accS[mt][nt] = (f32x4){0.f, 0.f, 0.f, 0.f};
#pragma unroll
        for (int k0 = 0; k0 < 2; ++k0)
#pragma unroll
            for (int nt = 0; nt < 4; ++nt) {
                f16x8 bk = *reinterpret_cast<const f16x8*>(
                    kg + (size_t)(st + nt * 16 + l15) * cHD + k0 * 32 + quad * 8);
#pragma unroll
                for (int mt = 0; mt < 2; ++mt)
                    accS[mt][nt] = __builtin_amdgcn_mfma_f32_16x16x32_f16(aq[mt][k0], bk, accS[mt][nt], 0, 0, 0);
            }
#pragma unroll
        for (int nt = 0; nt < 4; ++nt) {
            float pen = 1e9f * (1.0f - msk[step * 64 + nt * 16 + l15]);
#pragma unroll
            for (int mt = 0; mt < 2; ++mt)
#pragma unroll
                for (int r = 0; r < 4; ++r) accS[mt][nt][r] -= pen;
        }
#pragma unroll
        for (int mt = 0; mt < 2; ++mt) {
#pragma unroll
            for (int r = 0; r < 4; ++r) {
                float tmax = fmaxf(fmaxf(accS[mt][0][r], accS[mt][1][r]),
                                   fmaxf(accS[mt][2][r], accS[mt][3][r]));
#pragma unroll
                for (int w = 1; w < 16; w <<= 1) tmax = fmaxf(tmax, __shfl_xor(tmax, w, 16));
                float mnew = fmaxf(mrun[mt][r], tmax);
                float alpha = __expf(mrun[mt][r] - mnew);
                float ts = 0.f;
#pragma unroll
                for (int nt = 0; nt < 4; ++nt) {
                    float e = __expf(accS[mt][nt][r] - mnew);
                    accS[mt][nt][r] = e; ts += e;
                }
#pragma unroll
                for (int w = 1; w < 16; w <<= 1) ts += __shfl_xor(ts, w, 16);
                srun[mt][r] = srun[mt][r] * alpha + ts;
                mrun[mt][r] = mnew;
#pragma unroll
                for (int dt = 0; dt < 4; ++dt) accO[mt][dt][r] *= alpha;
            }
        }
#pragma unroll
        for (int mt = 0; mt < 2; ++mt)
#pragma unroll
            for (int nt = 0; nt < 4; ++nt)
#pragma unroll
                for (int r = 0; r < 4; ++r)
                    Ps[(wave * 32 + mt * 16 + quad * 4 + r) * 72 + nt * 16 + l15] =
                        (_Float16)accS[mt][nt][r];
#pragma unroll
        for (int k0 = 0; k0 < 2; ++k0) {
            f16x8 ap[2];
#pragma unroll
            for (int mt = 0; mt < 2; ++mt)
                ap[mt] = *reinterpret_cast<const f16x8*>(
                    &Ps[(wave * 32 + mt * 16 + l15) * 72 + k0 * 32 + quad * 8]);
#pragma unroll
            for (int dt = 0; dt < 4; ++dt) {
                f16x8 bv = *reinterpret_cast<const f16x8*>(
                    vg + (size_t)(dt * 16 + l15) * cS + st + k0 * 32 + quad * 8);
#pragma unroll
                for (int mt = 0; mt < 2; ++mt)
                    accO[mt][dt] = __builtin_amdgcn_mfma_f32_16x16x32_f16(ap[mt], bv, accO[mt][dt], 0, 0, 0);
            }
        }
    }
    const int rowbase = bh * cNL + wave * 32;
#pragma unroll
    for (int mt = 0; mt < 2; ++mt)
#pragma unroll
        for (int dt = 0; dt < 4; ++dt)
#pragma unroll
            for (int r = 0; r < 4; ++r)
                Opart[(size_t)(z * 4096 + rowbase + mt * 16 + quad * 4 + r) * cHD + dt * 16 + l15] =
                    accO[mt][dt][r];
    if (l15 == 0) {
#pragma unroll
        for (int mt = 0; mt < 2; ++mt)
#pragma unroll
            for (int r = 0; r < 4; ++r) {
                int prow = z * 4096 + rowbase + mt * 16 + quad * 4 + r;
                mpart[prow] = mrun[mt][r];
                spart[prow] = srun[mt][r];
            }
    }
}

// ---------------------------------------------------------------------------
// w2_matmul (+fused k3v_reduce): reduce 16 chunk partials into CVs (LDS),
// then U = M6 @ CV, then W2T[d][l] = (1/c) * sum_j k2[j][l] * U[j][d]
// ---------------------------------------------------------------------------
__global__ __launch_bounds__(256) void w2_matmul(
    const float* __restrict__ k2, const float* __restrict__ M6,
    const int* __restrict__ cmax,
    const float* __restrict__ Opart, const float* __restrict__ mpart,
    const float* __restrict__ spart,
    _Float16* __restrict__ W2T)
{
    __shared__ __align__(16) float CVs[128][68];
    __shared__ __align__(16) float Us[128][68];
    const int bh = blockIdx.x, t = threadIdx.x;
    const float invc = 1.0f / __int_as_float(*cmax);
    for (int it = 0; it < 32; ++it) {
        int idx = t + it * 256;
        int row = idx >> 6, d = idx & 63;
        int grow = bh * cNL + row;
        float mstar = -1e30f;
#pragma unroll
        for (int z = 0; z < 16; ++z) mstar = fmaxf(mstar, mpart[z * 4096 + grow]);
        float ssum = 0.f, acc = 0.f;
#pragma unroll
        for (int z = 0; z < 16; ++z) {
            float w = __expf(mpart[z * 4096 + grow] - mstar);
            ssum += w * spart[z * 4096 + grow];
            acc  += w * Opart[(size_t)(z * 4096 + grow) * cHD + d];
        }
        CVs[row][d] = acc / ssum;
    }
    __syncthreads();
    const float* Mg = M6 + (size_t)bh * 16384;
    {
        const int tx = t & 15, ty = t >> 4;
        float acc[8][4] = {};
        for (int k = 0; k < 128; ++k) {
            float4 b4 = *reinterpret_cast<const float4*>(&CVs[k][tx * 4]);
#pragma unroll
            for (int i = 0; i < 8; ++i) {
                float a = Mg[(ty * 8 + i) * 128 + k];
                acc[i][0] += a * b4.x; acc[i][1] += a * b4.y; acc[i][2] += a * b4.z; acc[i][3] += a * b4.w;
            }
        }
#pragma unroll
        for (int i = 0; i < 8; ++i)
#pragma unroll
            for (int j = 0; j < 4; ++j)
                Us[ty * 8 + i][tx * 4 + j] = acc[i][j];
    }
    __syncthreads();
    {
        const int l = t & 127, dg = (t >> 7) * 32;
        float acc2[32];
#pragma unroll
        for (int dd = 0; dd < 32; ++dd) acc2[dd] = 0.f;
        const float* kg = k2 + (size_t)bh * 16384;
        for (int j = 0; j < 128; ++j) {
            float kv = kg[j * 128 + l];
#pragma unroll
            for (int dd = 0; dd < 32; ++dd) acc2[dd] += kv * Us[j][dg + dd];
        }
        _Float16* wt = W2T + (size_t)bh * (cHD * cNL);
#pragma unroll
        for (int dd = 0; dd < 32; ++dd)
            wt[(size_t)(dg + dd) * cNL + l] = (_Float16)(acc2[dd] * invc);
    }
}

// ---------------------------------------------------------------------------
// k1_mfma (unchanged)
// ---------------------------------------------------------------------------
__global__ __launch_bounds__(256) void k1_mfma(
    const _Float16* __restrict__ Qh, const _Float16* __restrict__ Klh,
    const _Float16* __restrict__ W2T, _Float16* __restrict__ ctxh)
{
    __shared__ __align__(16) _Float16 Qs[64 * 72];
    __shared__ __align__(16) _Float16 Ps[64 * 136];
    const int s0 = blockIdx.x * 64, bh = blockIdx.y;
    const int b = bh >> 4, h = bh & 15;
    const int t = threadIdx.x;
    const int wave = t >> 6, lane = t & 63;
    const int quad = lane >> 4, l15 = lane & 15;

    {
        const _Float16* qg = Qh + ((size_t)bh * cS + s0) * cHD;
#pragma unroll
        for (int i = 0; i < 2; ++i) {
            int idx = t + i * 256;
            int row = idx >> 3, c8 = idx & 7;
            *reinterpret_cast<f16x8*>(&Qs[row * 72 + c8 * 8]) =
                *reinterpret_cast<const f16x8*>(qg + (size_t)row * cHD + c8 * 8);
        }
    }
    __syncthreads();

    const _Float16* klg = Klh + (size_t)bh * cNL * cHD;
    f32x4 accS[8];
#pragma unroll
    for (int nt = 0; nt < 8; ++nt) accS[nt] = (f32x4){0.f, 0.f, 0.f, 0.f};
#pragma unroll
    for (int k0 = 0; k0 < 2; ++k0) {
        f16x8 aq = *reinterpret_cast<const f16x8*>(&Qs[(wave * 16 + l15) * 72 + k0 * 32 + quad * 8]);
#pragma unroll
        for (int nt = 0; nt < 8; ++nt) {
            f16x8 bk = *reinterpret_cast<const f16x8*>(klg + (size_t)(nt * 16 + l15) * cHD + k0 * 32 + quad * 8);
            accS[nt] = __builtin_amdgcn_mfma_f32_16x16x32_f16(aq, bk, accS[nt], 0, 0, 0);
        }
    }

    float rmax[4] = {-1e30f, -1e30f, -1e30f, -1e30f};
#pragma unroll
    for (int nt = 0; nt < 8; ++nt)
#pragma unroll
        for (int r = 0; r < 4; ++r) rmax[r] = fmaxf(rmax[r], accS[nt][r]);
#pragma unroll
    for (int r = 0; r < 4; ++r)
#pragma unroll
        for (int w = 1; w < 16; w <<= 1) rmax[r] = fmaxf(rmax[r], __shfl_xor(rmax[r], w, 16));
    float rsum[4] = {0.f, 0.f, 0.f, 0.f};
#pragma unroll
    for (int nt = 0; nt < 8; ++nt)
#pragma unroll
        for (int r = 0; r < 4; ++r) { accS[nt][r] = __expf(accS[nt][r] - rmax[r]); rsum[r] += accS[nt][r]; }
#pragma unroll
    for (int r = 0; r < 4; ++r) {
#pragma unroll
        for (int w = 1; w < 16; w <<= 1) rsum[r] += __shfl_xor(rsum[r], w, 16);
        rsum[r] = 1.0f / rsum[r];
    }
#pragma unroll
    for (int nt = 0; nt < 8; ++nt)
#pragma unroll
        for (int r = 0; r < 4; ++r)
            Ps[(wave * 16 + quad * 4 + r) * 136 + nt * 16 + l15] = (_Float16)(accS[nt][r] * rsum[r]);
    __syncthreads();

    const _Float16* wtg = W2T + (size_t)bh * cHD * cNL;
    f32x4 accO[4];
#pragma unroll
    for (int nt = 0; nt < 4; ++nt) accO[nt] = (f32x4){0.f, 0.f, 0.f, 0.f};
#pragma unroll
    for (int k0 = 0; k0 < 4; ++k0) {
        f16x8 ap = *reinterpret_cast<const f16x8*>(&Ps[(wave * 16 + l15) * 136 + k0 * 32 + quad * 8]);
#pragma unroll
        for (int nt = 0; nt < 4; ++nt) {
            f16x8 bw = *reinterpret_cast<const f16x8*>(wtg + (size_t)(nt * 16 + l15) * cNL + k0 * 32 + quad * 8);
            accO[nt] = __builtin_amdgcn_mfma_f32_16x16x32_f16(ap, bw, accO[nt], 0, 0, 0);
        }
    }
#pragma unroll
    for (int nt = 0; nt < 4; ++nt)
#pragma unroll
        for (int r = 0; r < 4; ++r) {
            int s = s0 + wave * 16 + quad * 4 + r;
            int d = nt * 16 + l15;
            ctxh[((size_t)(b * cS) + s) * cD + h * cHD + d] = (_Float16)accO[nt][r];
        }
}

// ---------------------------------------------------------------------------
extern "C" void kernel_launch(void* const* d_in, const int* in_sizes, int n_in,
                              void* d_out, int out_size, void* d_ws, size_t ws_size,
                              hipStream_t stream)
{
    const float* X    = (const float*)d_in[0];
    const float* mask = (const float*)d_in[1];
    const float* Wq   = (const float*)d_in[2];
    const float* bq   = (const float*)d_in[3];
    const float* Wk   = (const float*)d_in[4];
    const float* bk   = (const float*)d_in[5];
    const float* Wv   = (const float*)d_in[6];
    const float* bv   = (const float*)d_in[7];
    const float* Wo   = (const float*)d_in[8];
    const float* bo   = (const float*)d_in[9];
    float* out = (float*)d_out;

    float* ws = (float*)d_ws;
    size_t off = 0;
    const size_t szQKV = (size_t)cBH * cS * cHD;      // 8388608 floats
    const size_t szL   = (size_t)cBH * cNL * cHD;     // 262144
    const size_t szM   = (size_t)cBH * cNL * cNL;     // 524288
    float* Qr   = ws + off; off += szQKV;             // Qh f16 (1st half) | Opart f32 (2nd half)
    float* Kr   = ws + off; off += szQKV;             // Kh f16 (1st half) | ctxh f16 (2nd half)
    float* Vr   = ws + off; off += szQKV;             // Vh f16 (1st half) | VTh f16 (2nd half)
    _Float16* Xh  = (_Float16*)(ws + off); off += szQKV / 2;
    _Float16* WqT = (_Float16*)(ws + off); off += 524288;
    _Float16* WkT = (_Float16*)(ws + off); off += 524288;
    _Float16* WvT = (_Float16*)(ws + off); off += 524288;
    _Float16* WoT = (_Float16*)(ws + off); off += 524288;
    float* Xm   = ws + off; off += (size_t)cB * cNL * cHID;
    float* mbar = ws + off; off += 256;
    float* Ql  = ws + off; off += szL;
    float* Kl  = ws + off; off += szL;
    float* k2  = ws + off; off += szM;
    float* Mg0 = ws + off; off += szM;                // M double-buffer 0
    float* Mg1 = ws + off; off += szM;                // M double-buffer 1
    float* T1b = ws + off; off += szM;                // (unused)
    float* T2b = ws + off; off += szM;                // (unused)
    float* T3b = ws + off; off += szM;                // (unused)
    float* CV  = ws + off; off += szL;                // (unused now)
    _Float16* Qlh  = (_Float16*)(ws + off); off += szL / 2;
    _Float16* Klh  = (_Float16*)(ws + off); off += szL / 2;
    _Float16* W2Th = (_Float16*)(ws + off); off += szL / 2;
    int*   cmax = (int*)(ws + off); off += 16;
    float* mpart = ws + off; off += 65536;
    float* spart = ws + off; off += 65536;

    _Float16* Qh   = (_Float16*)Qr;
    float*    Opart = Qr + szQKV / 2;        // 2nd half of Q region (Qh untouched)
    _Float16* Kh   = (_Float16*)Kr;
    _Float16* ctxh = (_Float16*)(Kr + szQKV / 2);   // 2nd half of K region
    _Float16* Vh   = (_Float16*)Vr;
    _Float16* VTh  = (_Float16*)(Vr + szQKV / 2);   // 2nd half of V region

    (void)T1b; (void)T2b; (void)T3b; (void)CV;

    hipMemsetAsync(cmax, 0, sizeof(int), stream);

    wcast_t<<<dim3(32, 32, 4), 256, 0, stream>>>(Wq, Wk, Wv, Wo, WqT, WkT, WvT, WoT);
    xm_kernel<<<dim3(cB * cNL, 4), 64, 0, stream>>>(X, mask, Xm, mbar, Xh);

    // landmark chain first (independent of qkv) so nys inputs are ready
    lgemm<<<dim3(cD / 64, (cB * cNL) / 64, 2), 256, 0, stream>>>(Xm, mbar, Wq, bq, Wk, bk, Ql, Kl, Qlh, Klh);
    k2_softmax<<<cBH * cNL, 128, 0, stream>>>(Ql, Kl, k2);
    colsum_max<<<cBH, 128, 0, stream>>>(k2, cmax);

    // fused: Newton-Schulz (32 blocks) overlapped with QKV GEMM (768 dual-tile blocks)
    nys_qkv<<<dim3(32 + 768), 512, 0, stream>>>(
        k2, cmax, Mg0, Mg1,
        Xh, mask, WqT, WkT, WvT, bq, bk, bv, Qh, Kh, Vh);

    vtrans<<<dim3(cS / 64, cBH), 256, 0, stream>>>(Vh, VTh);
    k3v_mfma<<<dim3(16, cBH), 256, 0, stream>>>(Qlh, Kh, VTh, mask, Opart, mpart, spart);

    // W2 = (K^T/c) @ M6 @ (reduced CV), reduce fused in
    w2_matmul<<<cBH, 256, 0, stream>>>(k2, Mg1, cmax, Opart, mpart, spart, W2Th);
    k1_mfma<<<dim3(cS / 64, cBH), 256, 0, stream>>>(Qh, Klh, W2Th, ctxh);
    out_gemm_f16<<<dim3(512), 256, 0, stream>>>(ctxh, WoT, bo, out);
}